// Round 10
// baseline (4053.456 us; speedup 1.0000x reference)
//
#include <hip/hip_runtime.h>
#include <hip/hip_bf16.h>

#define NNODES 50000
#define NEDGES 300000
#define NL 6
#define AP 132   // fp32 A-tile row pitch: 128 + 4 pad

// ---------- tiny setup kernels ----------
__global__ void k_gf(const float* dom, const float* t, const float* xg,
                     const float* domn, const float* tn, float* gf){
  int i = threadIdx.x;
  if(i < 3)        gf[i]  = dom[i];
  else if(i == 3)  gf[3]  = t[0];
  else if(i < 8)   gf[i]  = xg[i-4];
  else if(i < 11)  gf[i]  = domn[i-8];
  else if(i == 11) gf[11] = tn[0];
}

__global__ void k_deg(const int* ei, float* deg){
  int e = blockIdx.x*blockDim.x + threadIdx.x;
  if(e < NEDGES) atomicAdd(&deg[ei[NEDGES + e]], 1.0f);
}

__global__ void k_histi(const int* ei, int* cnt){
  int e = blockIdx.x*blockDim.x + threadIdx.x;
  if(e < NEDGES) atomicAdd(&cnt[ei[NEDGES + e]], 1);
}

// single-block exclusive scan of cnt[NNODES] -> off[NNODES+1]
__global__ __launch_bounds__(1024) void k_scan(const int* cnt, int* off){
  __shared__ int buf[1024];
  __shared__ int carry;
  int t = threadIdx.x;
  if(t == 0) carry = 0;
  __syncthreads();
  for(int base = 0; base < NNODES; base += 1024){
    int i = base + t;
    int x = (i < NNODES) ? cnt[i] : 0;
    buf[t] = x;
    __syncthreads();
    for(int ofs = 1; ofs < 1024; ofs <<= 1){
      int y = (t >= ofs) ? buf[t-ofs] : 0;
      __syncthreads();
      buf[t] += y;
      __syncthreads();
    }
    if(i < NNODES) off[i] = carry + buf[t] - x;
    __syncthreads();
    if(t == 1023) carry += buf[1023];
    __syncthreads();
  }
  if(t == 0) off[NNODES] = carry;
}

// counting-sort scatter: edges grouped by dst
__global__ void k_scatter(const int* ei, const int* off, int* cur, int* srcP, int* dstP){
  int e = blockIdx.x*blockDim.x + threadIdx.x;
  if(e < NEDGES){
    int s = ei[e], d = ei[NEDGES + e];
    int p = atomicAdd(&cur[d], 1);
    int ix = off[d] + p;
    srcP[ix] = s; dstP[ix] = d;
  }
}

// bb1[l][c] = msgB1[l][c] + sum_j gf[j]*msgW1[l][267+j][c]
__global__ void k_gfb(const float* gf, const float* mW1, const float* mB1, float* bb1){
  int i = blockIdx.x*256 + threadIdx.x;
  if(i < 768){
    int l = i >> 7, c = i & 127;
    float s = mB1[l*128 + c];
    #pragma unroll
    for(int j=0;j<12;j++) s = fmaf(gf[j], mW1[(size_t)l*35712 + (size_t)(267+j)*128 + c], s);
    bb1[i] = s;
  }
}

// ---------- shared fp32 GEMM machinery (32-row, fallback kernels) ----------
__device__ __forceinline__ void fill_w(float* sW, const float* gW, int KC){
  for(int idx = threadIdx.x; idx < 32*32; idx += 256){
    int kk = idx >> 5, c4 = (idx & 31)*4;
    float4 w = make_float4(0.f,0.f,0.f,0.f);
    if(kk < KC) w = *(const float4*)(gW + (size_t)kk*128 + c4);
    *(float4*)(sW + kk*128 + c4) = w;
  }
}
__device__ __forceinline__ void gemm_chunk(const float* At, const float* sW,
                                           int KCp, int rg, int jc, float acc[4][4]){
  for(int kkg = 0; kkg < KCp; kkg += 4){
    float4 av[4];
    #pragma unroll
    for(int i=0;i<4;i++) av[i] = *(const float4*)(At + (rg*4+i)*AP + kkg);
    #pragma unroll
    for(int q=0;q<4;q++){
      float4 bq = *(const float4*)(sW + (kkg+q)*128 + 4*jc);
      #pragma unroll
      for(int i=0;i<4;i++){
        float aa = ((const float*)&av[i])[q];
        acc[i][0] = fmaf(aa, bq.x, acc[i][0]);
        acc[i][1] = fmaf(aa, bq.y, acc[i][1]);
        acc[i][2] = fmaf(aa, bq.z, acc[i][2]);
        acc[i][3] = fmaf(aa, bq.w, acc[i][3]);
      }
    }
  }
}
__device__ __forceinline__ void gemm_phase(const float* sA, float* sW, const float* gW,
                                           int K, int rg, int jc, float acc[4][4]){
  for(int k0 = 0; k0 < K; k0 += 32){
    int KC = (K - k0 < 32) ? (K - k0) : 32;
    __syncthreads();
    fill_w(sW, gW + (size_t)k0*128, KC);
    __syncthreads();
    gemm_chunk(sA + k0, sW, (KC+3)&~3, rg, jc, acc);
  }
}
__device__ __forceinline__ void init_bias(float acc[4][4], const float* b, int jc){
  float4 bb = *(const float4*)(b + 4*jc);
  #pragma unroll
  for(int i=0;i<4;i++){ acc[i][0]=bb.x; acc[i][1]=bb.y; acc[i][2]=bb.z; acc[i][3]=bb.w; }
}

// ---------- 64-row GEMM machinery (8 rows x 4 cols per thread) ----------
// rg = t>>5 (0..7) owns rows rg*8..rg*8+7; jc = t&31 owns cols 4jc..4jc+3.
// Per chunk per thread: 96 ds_read_b128 for 1024 FMA (10.7 FMA/read vs 8 at 4x4).
__device__ __forceinline__ void gemm_chunk64(const float* At, const float* sW,
                                             int KCp, int rg, int jc, float acc[8][4]){
  for(int kkg = 0; kkg < KCp; kkg += 4){
    float4 av[8];
    #pragma unroll
    for(int i=0;i<8;i++) av[i] = *(const float4*)(At + (rg*8+i)*AP + kkg);
    #pragma unroll
    for(int q=0;q<4;q++){
      float4 bq = *(const float4*)(sW + (kkg+q)*128 + 4*jc);
      #pragma unroll
      for(int i=0;i<8;i++){
        float aa = ((const float*)&av[i])[q];
        acc[i][0] = fmaf(aa, bq.x, acc[i][0]);
        acc[i][1] = fmaf(aa, bq.y, acc[i][1]);
        acc[i][2] = fmaf(aa, bq.z, acc[i][2]);
        acc[i][3] = fmaf(aa, bq.w, acc[i][3]);
      }
    }
  }
}
__device__ __forceinline__ void gemm_phase64(const float* sA, float* sW, const float* gW,
                                             int K, int rg, int jc, float acc[8][4]){
  for(int k0 = 0; k0 < K; k0 += 32){
    int KC = (K - k0 < 32) ? (K - k0) : 32;
    __syncthreads();
    fill_w(sW, gW + (size_t)k0*128, KC);
    __syncthreads();
    gemm_chunk64(sA + k0, sW, (KC+3)&~3, rg, jc, acc);
  }
}
__device__ __forceinline__ void init_bias64(float acc[8][4], const float* b, int jc){
  float4 bb = *(const float4*)(b + 4*jc);
  #pragma unroll
  for(int i=0;i<8;i++){ acc[i][0]=bb.x; acc[i][1]=bb.y; acc[i][2]=bb.z; acc[i][3]=bb.w; }
}

// ---------- embedding (32-row, unchanged) ----------
__global__ __launch_bounds__(256) void k_embed(const float* r, const float* v, const float* gf,
    const float* W1, const float* b1, const float* W2, const float* b2, float* h){
  __shared__ __align__(16) float sA[32*AP];
  __shared__ __align__(16) float sW[32*128];
  __shared__ float sGf[12];
  int t = threadIdx.x, n0 = blockIdx.x*32;
  if(t < 12) sGf[t] = gf[t];
  __syncthreads();
  for(int idx = t; idx < 32*20; idx += 256){
    int row = idx/20, c = idx%20;
    int n = n0 + row; if(n >= NNODES) n = NNODES-1;
    float val;
    if(c == 0)      val = r[n];
    else if(c < 7)  val = v[(size_t)n*6 + (c-1)];
    else if(c < 19) val = sGf[c-7];
    else            val = 0.0f;
    sA[row*AP + c] = val;
  }
  int rg = t>>5, jc = t&31;
  float acc[4][4];
  init_bias(acc, b1, jc);
  gemm_phase(sA, sW, W1, 19, rg, jc, acc);
  __syncthreads();
  #pragma unroll
  for(int i=0;i<4;i++){
    float4 x = make_float4(fmaxf(acc[i][0],0.f), fmaxf(acc[i][1],0.f),
                           fmaxf(acc[i][2],0.f), fmaxf(acc[i][3],0.f));
    *(float4*)&sA[(rg*4+i)*AP + 4*jc] = x;
  }
  init_bias(acc, b2, jc);
  gemm_phase(sA, sW, W2, 128, rg, jc, acc);
  #pragma unroll
  for(int i=0;i<4;i++){
    int n = n0 + rg*4 + i;
    if(n < NNODES){
      float4 x = make_float4(fmaxf(acc[i][0],0.f), fmaxf(acc[i][1],0.f),
                             fmaxf(acc[i][2],0.f), fmaxf(acc[i][3],0.f));
      *(float4*)&h[(size_t)n*128 + 4*jc] = x;
    }
  }
}

// ---------- fused norm + P precompute, 64-row ----------
__global__ __launch_bounds__(256) void k_pre2b(float* h, const float* W1, float* P,
                                               const float* S, int doNorm){
  __shared__ __align__(16) float sA[64*AP];
  __shared__ __align__(16) float sW[32*128];
  __shared__ float sMu[128], sIv[128];
  int t = threadIdx.x, n0 = blockIdx.x*64;
  if(doNorm){
    if(t < 128){
      float mean = S[t] * (1.0f/NNODES);
      float var  = S[128+t] * (1.0f/NNODES) - mean*mean;
      if(var < 0.f) var = 0.f;
      sMu[t] = mean; sIv[t] = rsqrtf(var + 1e-5f);
    }
    __syncthreads();
    for(int idx = t; idx < 2048; idx += 256){
      int row = idx>>5, c4 = (idx&31)*4;
      int n = n0 + row; bool valid = (n < NNODES); if(!valid) n = NNODES-1;
      float4 x = *(const float4*)&h[(size_t)n*128 + c4];
      x.x = (x.x - sMu[c4+0])*sIv[c4+0];
      x.y = (x.y - sMu[c4+1])*sIv[c4+1];
      x.z = (x.z - sMu[c4+2])*sIv[c4+2];
      x.w = (x.w - sMu[c4+3])*sIv[c4+3];
      *(float4*)&sA[row*AP + c4] = x;
      if(valid) *(float4*)&h[(size_t)n*128 + c4] = x;  // persist normalized h
    }
  } else {
    for(int idx = t; idx < 2048; idx += 256){
      int row = idx>>5, c4 = (idx&31)*4;
      int n = n0 + row; if(n >= NNODES) n = NNODES-1;
      *(float4*)&sA[row*AP + c4] = *(const float4*)&h[(size_t)n*128 + c4];
    }
  }
  int rg = t>>5, jc = t&31;
  float acc[8][4];
  #pragma unroll
  for(int i=0;i<8;i++){ acc[i][0]=0.f; acc[i][1]=0.f; acc[i][2]=0.f; acc[i][3]=0.f; }
  gemm_phase64(sA, sW, W1, 128, rg, jc, acc);               // W1a
  #pragma unroll
  for(int i=0;i<8;i++){
    int n = n0 + rg*8 + i;
    if(n < NNODES)
      *(float4*)&P[(size_t)n*256 + 4*jc] = make_float4(acc[i][0],acc[i][1],acc[i][2],acc[i][3]);
  }
  #pragma unroll
  for(int i=0;i<8;i++){ acc[i][0]=0.f; acc[i][1]=0.f; acc[i][2]=0.f; acc[i][3]=0.f; }
  gemm_phase64(sA, sW, W1 + (size_t)128*128, 128, rg, jc, acc);  // W1b
  #pragma unroll
  for(int i=0;i<8;i++){
    int n = n0 + rg*8 + i;
    if(n < NNODES)
      *(float4*)&P[(size_t)n*256 + 128 + 4*jc] = make_float4(acc[i][0],acc[i][1],acc[i][2],acc[i][3]);
  }
}

// ---------- edge kernel, 64 edges/block, dst-sorted + segment-reduced ----------
__global__ __launch_bounds__(256) void k_msg3b(const int* srcP, const int* dstP, const float* P,
    const float* pos, const float* v, const float* r, const float* dom,
    const float* W1, const float* W2, const float* bb1, const float* b2, float* agg){
  __shared__ __align__(16) float sM[64*AP];
  __shared__ __align__(16) float sW[32*128];
  __shared__ float sT[64*12];
  __shared__ float sB[128];
  __shared__ int sSrc[64], sDst[64];
  int t = threadIdx.x, e0 = blockIdx.x*64;
  if(t < 64){
    int e = e0 + t; if(e >= NEDGES) e = NEDGES-1;
    sSrc[t] = srcP[e]; sDst[t] = dstP[e];
  }
  if(t >= 128) sB[t-128] = bb1[t-128];
  __syncthreads();
  // W1c rows 0..10 into sW
  for(int idx = t; idx < 352; idx += 256){
    int kk = idx>>5, c4 = (idx&31)*4;
    *(float4*)&sW[kk*128 + c4] = *(const float4*)&W1[(size_t)(256+kk)*128 + c4];
  }
  // tail: dpos(3), dv(6), r_dst, r_src
  if(t < 64){
    int s = sSrc[t], d = sDst[t];
    #pragma unroll
    for(int c=0;c<3;c++){
      float dp = pos[(size_t)d*3+c] - pos[(size_t)s*3+c];
      float dm = dom[c];
      dp = dp - dm * rintf(dp/dm);
      sT[t*12 + c] = dp;
    }
    #pragma unroll
    for(int c=0;c<6;c++)
      sT[t*12 + 3 + c] = v[(size_t)d*6+c] - v[(size_t)s*6+c];
    sT[t*12 + 9]  = r[d];
    sT[t*12 + 10] = r[s];
    sT[t*12 + 11] = 0.0f;
  }
  // z1 gather
  for(int idx = t; idx < 2048; idx += 256){
    int row = idx>>5, c4 = (idx&31)*4;
    float4 pd = *(const float4*)&P[(size_t)sDst[row]*256 + c4];
    float4 ps = *(const float4*)&P[(size_t)sSrc[row]*256 + 128 + c4];
    float4 bb = *(const float4*)&sB[c4];
    *(float4*)&sM[row*AP + c4] = make_float4(bb.x+pd.x+ps.x, bb.y+pd.y+ps.y,
                                             bb.z+pd.z+ps.z, bb.w+pd.w+ps.w);
  }
  __syncthreads();
  int rg = t>>5, jc = t&31;
  float acc[8][4];
  #pragma unroll
  for(int i=0;i<8;i++)
    #pragma unroll
    for(int c=0;c<4;c++) acc[i][c] = sM[(rg*8+i)*AP + 4*jc + c];
  for(int k=0;k<11;k++){
    float4 b = *(const float4*)&sW[k*128 + 4*jc];
    #pragma unroll
    for(int i=0;i<8;i++){
      float a = sT[(rg*8+i)*12 + k];
      acc[i][0] = fmaf(a, b.x, acc[i][0]);
      acc[i][1] = fmaf(a, b.y, acc[i][1]);
      acc[i][2] = fmaf(a, b.z, acc[i][2]);
      acc[i][3] = fmaf(a, b.w, acc[i][3]);
    }
  }
  // relu -> hidden
  #pragma unroll
  for(int i=0;i<8;i++){
    float4 x = make_float4(fmaxf(acc[i][0],0.f), fmaxf(acc[i][1],0.f),
                           fmaxf(acc[i][2],0.f), fmaxf(acc[i][3],0.f));
    *(float4*)&sM[(rg*8+i)*AP + 4*jc] = x;
  }
  // MLP2 (K=128)
  init_bias64(acc, b2, jc);
  gemm_phase64(sM, sW, W2, 128, rg, jc, acc);
  __syncthreads();
  // relu(m) (zero for invalid/padded edges) -> sM
  #pragma unroll
  for(int i=0;i<8;i++){
    int row = rg*8 + i;
    float4 x;
    if(e0 + row < NEDGES)
      x = make_float4(fmaxf(acc[i][0],0.f), fmaxf(acc[i][1],0.f),
                      fmaxf(acc[i][2],0.f), fmaxf(acc[i][3],0.f));
    else
      x = make_float4(0.f,0.f,0.f,0.f);
    *(float4*)&sM[row*AP + 4*jc] = x;
  }
  __syncthreads();
  // segment reduce: 128 threads/half, 32 rows each
  int col = t & 127, half = t >> 7;
  int rbeg = half*32, rend = rbeg + 32;
  int cur = sDst[rbeg];
  float run = 0.f;
  for(int row = rbeg; row < rend; row++){
    run += sM[row*AP + col];
    int nxt = (row+1 < rend) ? sDst[row+1] : -1;
    if(nxt != cur){
      atomicAdd(&agg[(size_t)cur*128 + col], run);
      run = 0.f; cur = nxt;
    }
  }
}

// ---------- fused node update, 64-row: h += MLP; zeros agg; stats -> S ----------
__global__ __launch_bounds__(256) void k_upd2b(float* h, float* agg, const int* cnt,
    const float* gf, const float* W1, const float* b1, const float* W2, const float* b2,
    float* S){
  __shared__ __align__(16) float sA[64*AP];
  __shared__ __align__(16) float sW[32*128];
  __shared__ float sGf[12], sRd[64];
  int t = threadIdx.x, n0 = blockIdx.x*64;
  if(t < 12) sGf[t] = gf[t];
  if(t < 64){
    int n = n0 + t; if(n >= NNODES) n = NNODES-1;
    sRd[t] = 1.0f / fmaxf((float)cnt[n], 1.0f);
  }
  __syncthreads();
  int rg = t>>5, jc = t&31;
  float acc[8][4];
  init_bias64(acc, b1, jc);
  // phase 1: h
  for(int idx = t; idx < 2048; idx += 256){
    int row = idx>>5, c4 = (idx&31)*4;
    int n = n0 + row; if(n >= NNODES) n = NNODES-1;
    *(float4*)&sA[row*AP + c4] = *(const float4*)&h[(size_t)n*128 + c4];
  }
  gemm_phase64(sA, sW, W1, 128, rg, jc, acc);
  __syncthreads();
  // phase 2: agg/deg + re-zero agg (valid rows only)
  for(int idx = t; idx < 2048; idx += 256){
    int row = idx>>5, c4 = (idx&31)*4;
    int n = n0 + row; bool valid = (n < NNODES); if(!valid) n = NNODES-1;
    float4 x = *(const float4*)&agg[(size_t)n*128 + c4];
    float rd = sRd[row];
    x.x*=rd; x.y*=rd; x.z*=rd; x.w*=rd;
    *(float4*)&sA[row*AP + c4] = x;
    if(valid) *(float4*)&agg[(size_t)n*128 + c4] = make_float4(0.f,0.f,0.f,0.f);
  }
  gemm_phase64(sA, sW, W1 + (size_t)128*128, 128, rg, jc, acc);
  __syncthreads();
  // phase 3: gf (12)
  if(t < 64){
    #pragma unroll
    for(int c=0;c<12;c++) sA[t*AP + c] = sGf[c];
  }
  gemm_phase64(sA, sW, W1 + (size_t)256*128, 12, rg, jc, acc);
  __syncthreads();
  #pragma unroll
  for(int i=0;i<8;i++){
    float4 x = make_float4(fmaxf(acc[i][0],0.f), fmaxf(acc[i][1],0.f),
                           fmaxf(acc[i][2],0.f), fmaxf(acc[i][3],0.f));
    *(float4*)&sA[(rg*8+i)*AP + 4*jc] = x;
  }
  init_bias64(acc, b2, jc);
  gemm_phase64(sA, sW, W2, 128, rg, jc, acc);   // no relu
  // skip connection + write h + per-thread stats
  float sc[4] = {0.f,0.f,0.f,0.f}, qc[4] = {0.f,0.f,0.f,0.f};
  #pragma unroll
  for(int i=0;i<8;i++){
    int n = n0 + rg*8 + i;
    if(n < NNODES){
      float4 x = *(const float4*)&h[(size_t)n*128 + 4*jc];
      x.x += acc[i][0]; x.y += acc[i][1]; x.z += acc[i][2]; x.w += acc[i][3];
      *(float4*)&h[(size_t)n*128 + 4*jc] = x;
      sc[0]+=x.x; sc[1]+=x.y; sc[2]+=x.z; sc[3]+=x.w;
      qc[0]+=x.x*x.x; qc[1]+=x.y*x.y; qc[2]+=x.z*x.z; qc[3]+=x.w*x.w;
    }
  }
  __syncthreads();   // all gemm reads of sA done; reuse sA for stat partials
  #pragma unroll
  for(int c=0;c<4;c++){
    sA[rg*128 + 4*jc + c]        = sc[c];
    sA[1024 + rg*128 + 4*jc + c] = qc[c];
  }
  __syncthreads();
  if(t < 128){
    float s = 0.f, q = 0.f;
    #pragma unroll
    for(int g=0; g<8; g++){ s += sA[g*128 + t]; q += sA[1024 + g*128 + t]; }
    atomicAdd(&S[t], s);
    atomicAdd(&S[128 + t], q);
  }
}

// ---------- fallback kernels (round-6 / round-3 tiers, verbatim) ----------
__global__ __launch_bounds__(256) void k_msg2(const int* ei, const float* P,
    const float* pos, const float* v, const float* r, const float* dom,
    const float* W1, const float* W2, const float* bb1, const float* b2, float* agg){
  __shared__ __align__(16) float sM[32*AP];
  __shared__ __align__(16) float sW[32*128];
  __shared__ float sT[32*12];
  __shared__ float sB[128];
  __shared__ int sSrc[32], sDst[32];
  int t = threadIdx.x, e0 = blockIdx.x*32;
  if(t < 32){ sSrc[t] = ei[e0+t]; sDst[t] = ei[NEDGES + e0 + t]; }
  if(t >= 128) sB[t-128] = bb1[t-128];
  __syncthreads();
  for(int idx = t; idx < 352; idx += 256){
    int kk = idx>>5, c4 = (idx&31)*4;
    *(float4*)&sW[kk*128 + c4] = *(const float4*)&W1[(size_t)(256+kk)*128 + c4];
  }
  if(t < 32){
    int s = sSrc[t], d = sDst[t];
    #pragma unroll
    for(int c=0;c<3;c++){
      float dp = pos[(size_t)d*3+c] - pos[(size_t)s*3+c];
      float dm = dom[c];
      dp = dp - dm * rintf(dp/dm);
      sT[t*12 + c] = dp;
    }
    #pragma unroll
    for(int c=0;c<6;c++)
      sT[t*12 + 3 + c] = v[(size_t)d*6+c] - v[(size_t)s*6+c];
    sT[t*12 + 9]  = r[d];
    sT[t*12 + 10] = r[s];
    sT[t*12 + 11] = 0.0f;
  }
  for(int idx = t; idx < 1024; idx += 256){
    int row = idx>>5, c4 = (idx&31)*4;
    float4 pd = *(const float4*)&P[(size_t)sDst[row]*256 + c4];
    float4 ps = *(const float4*)&P[(size_t)sSrc[row]*256 + 128 + c4];
    float4 bb = *(const float4*)&sB[c4];
    *(float4*)&sM[row*AP + c4] = make_float4(bb.x+pd.x+ps.x, bb.y+pd.y+ps.y,
                                             bb.z+pd.z+ps.z, bb.w+pd.w+ps.w);
  }
  __syncthreads();
  int rg = t>>5, jc = t&31;
  float acc[4][4];
  #pragma unroll
  for(int i=0;i<4;i++)
    #pragma unroll
    for(int c=0;c<4;c++) acc[i][c] = sM[(rg*4+i)*AP + 4*jc + c];
  for(int k=0;k<11;k++){
    float4 b = *(const float4*)&sW[k*128 + 4*jc];
    #pragma unroll
    for(int i=0;i<4;i++){
      float a = sT[(rg*4+i)*12 + k];
      acc[i][0] = fmaf(a, b.x, acc[i][0]);
      acc[i][1] = fmaf(a, b.y, acc[i][1]);
      acc[i][2] = fmaf(a, b.z, acc[i][2]);
      acc[i][3] = fmaf(a, b.w, acc[i][3]);
    }
  }
  #pragma unroll
  for(int i=0;i<4;i++){
    float4 x = make_float4(fmaxf(acc[i][0],0.f), fmaxf(acc[i][1],0.f),
                           fmaxf(acc[i][2],0.f), fmaxf(acc[i][3],0.f));
    *(float4*)&sM[(rg*4+i)*AP + 4*jc] = x;
  }
  init_bias(acc, b2, jc);
  gemm_phase(sM, sW, W2, 128, rg, jc, acc);
  #pragma unroll
  for(int i=0;i<4;i++){
    int d = sDst[rg*4+i];
    #pragma unroll
    for(int c=0;c<4;c++)
      atomicAdd(&agg[(size_t)d*128 + 4*jc + c], fmaxf(acc[i][c], 0.0f));
  }
}

__global__ __launch_bounds__(256) void k_pre(const float* h, const float* W1, float* P){
  __shared__ __align__(16) float sA[32*AP];
  __shared__ __align__(16) float sW[32*128];
  int t = threadIdx.x, n0 = blockIdx.x*32;
  for(int idx = t; idx < 1024; idx += 256){
    int row = idx>>5, c4 = (idx&31)*4;
    int n = n0 + row; if(n >= NNODES) n = NNODES-1;
    *(float4*)&sA[row*AP + c4] = *(const float4*)&h[(size_t)n*128 + c4];
  }
  int rg = t>>5, jc = t&31;
  float acc[4][4];
  #pragma unroll
  for(int i=0;i<4;i++){ acc[i][0]=0.f; acc[i][1]=0.f; acc[i][2]=0.f; acc[i][3]=0.f; }
  gemm_phase(sA, sW, W1, 128, rg, jc, acc);
  #pragma unroll
  for(int i=0;i<4;i++){
    int n = n0 + rg*4 + i;
    if(n < NNODES)
      *(float4*)&P[(size_t)n*256 + 4*jc] = make_float4(acc[i][0],acc[i][1],acc[i][2],acc[i][3]);
  }
  #pragma unroll
  for(int i=0;i<4;i++){ acc[i][0]=0.f; acc[i][1]=0.f; acc[i][2]=0.f; acc[i][3]=0.f; }
  gemm_phase(sA, sW, W1 + (size_t)128*128, 128, rg, jc, acc);
  #pragma unroll
  for(int i=0;i<4;i++){
    int n = n0 + rg*4 + i;
    if(n < NNODES)
      *(float4*)&P[(size_t)n*256 + 128 + 4*jc] = make_float4(acc[i][0],acc[i][1],acc[i][2],acc[i][3]);
  }
}

__global__ __launch_bounds__(256) void k_msg_old(const int* ei, const float* h,
    const float* pos, const float* v, const float* r, const float* dom, const float* gf,
    const float* W1, const float* b1, const float* W2, const float* b2, float* agg, int l){
  __shared__ __align__(16) float sA[32*AP];
  __shared__ __align__(16) float sW[32*128];
  __shared__ int sSrc[32], sDst[32];
  __shared__ float sGf[12];
  int t = threadIdx.x, e0 = blockIdx.x*32;
  if(t < 32){ sSrc[t] = ei[e0+t]; sDst[t] = ei[NEDGES + e0 + t]; }
  if(t >= 32 && t < 44) sGf[t-32] = gf[t-32];
  __syncthreads();
  const float* Wl1 = W1 + (size_t)l*35712;
  const float* Wl2 = W2 + (size_t)l*16384;
  const float* bl1 = b1 + l*128;
  const float* bl2 = b2 + l*128;
  int rg = t>>5, jc = t&31;
  float acc[4][4];
  init_bias(acc, bl1, jc);
  for(int idx = t; idx < 1024; idx += 256){
    int row = idx>>5, c4 = (idx&31)*4;
    *(float4*)&sA[row*AP + c4] = *(const float4*)&h[(size_t)sDst[row]*128 + c4];
  }
  gemm_phase(sA, sW, Wl1, 128, rg, jc, acc);
  __syncthreads();
  for(int idx = t; idx < 1024; idx += 256){
    int row = idx>>5, c4 = (idx&31)*4;
    *(float4*)&sA[row*AP + c4] = *(const float4*)&h[(size_t)sSrc[row]*128 + c4];
  }
  gemm_phase(sA, sW, Wl1 + (size_t)128*128, 128, rg, jc, acc);
  __syncthreads();
  if(t < 32){
    int s = sSrc[t], d = sDst[t];
    #pragma unroll
    for(int c=0;c<3;c++){
      float dp = pos[(size_t)d*3+c] - pos[(size_t)s*3+c];
      float dm = dom[c];
      dp = dp - dm * rintf(dp/dm);
      sA[t*AP + c] = dp;
    }
    #pragma unroll
    for(int c=0;c<6;c++)
      sA[t*AP + 3 + c] = v[(size_t)d*6+c] - v[(size_t)s*6+c];
    sA[t*AP + 9]  = r[d];
    sA[t*AP + 10] = r[s];
    #pragma unroll
    for(int c=0;c<12;c++) sA[t*AP + 11 + c] = sGf[c];
    sA[t*AP + 23] = 0.0f;
  }
  gemm_phase(sA, sW, Wl1 + (size_t)256*128, 23, rg, jc, acc);
  __syncthreads();
  #pragma unroll
  for(int i=0;i<4;i++){
    float4 x = make_float4(fmaxf(acc[i][0],0.f), fmaxf(acc[i][1],0.f),
                           fmaxf(acc[i][2],0.f), fmaxf(acc[i][3],0.f));
    *(float4*)&sA[(rg*4+i)*AP + 4*jc] = x;
  }
  init_bias(acc, bl2, jc);
  gemm_phase(sA, sW, Wl2, 128, rg, jc, acc);
  #pragma unroll
  for(int i=0;i<4;i++){
    int d = sDst[rg*4+i];
    #pragma unroll
    for(int c=0;c<4;c++)
      atomicAdd(&agg[(size_t)d*128 + 4*jc + c], fmaxf(acc[i][c], 0.0f));
  }
}

__global__ __launch_bounds__(256) void k_upd(float* h, const float* agg, const float* deg,
    const float* gf, const float* W1, const float* b1, const float* W2, const float* b2, int l){
  __shared__ __align__(16) float sA[32*AP];
  __shared__ __align__(16) float sW[32*128];
  __shared__ float sGf[12], sRd[32];
  int t = threadIdx.x, n0 = blockIdx.x*32;
  if(t < 12) sGf[t] = gf[t];
  if(t < 32){
    int n = n0 + t; if(n >= NNODES) n = NNODES-1;
    sRd[t] = 1.0f / fmaxf(deg[n], 1.0f);
  }
  __syncthreads();
  const float* Wl1 = W1 + (size_t)l*34304;
  const float* Wl2 = W2 + (size_t)l*16384;
  const float* bl1 = b1 + l*128;
  const float* bl2 = b2 + l*128;
  int rg = t>>5, jc = t&31;
  float acc[4][4];
  init_bias(acc, bl1, jc);
  for(int idx = t; idx < 1024; idx += 256){
    int row = idx>>5, c4 = (idx&31)*4;
    int n = n0 + row; if(n >= NNODES) n = NNODES-1;
    *(float4*)&sA[row*AP + c4] = *(const float4*)&h[(size_t)n*128 + c4];
  }
  gemm_phase(sA, sW, Wl1, 128, rg, jc, acc);
  __syncthreads();
  for(int idx = t; idx < 1024; idx += 256){
    int row = idx>>5, c4 = (idx&31)*4;
    int n = n0 + row; if(n >= NNODES) n = NNODES-1;
    float4 x = *(const float4*)&agg[(size_t)n*128 + c4];
    float rd = sRd[row];
    x.x*=rd; x.y*=rd; x.z*=rd; x.w*=rd;
    *(float4*)&sA[row*AP + c4] = x;
  }
  gemm_phase(sA, sW, Wl1 + (size_t)128*128, 128, rg, jc, acc);
  __syncthreads();
  if(t < 32){
    #pragma unroll
    for(int c=0;c<12;c++) sA[t*AP + c] = sGf[c];
  }
  gemm_phase(sA, sW, Wl1 + (size_t)256*128, 12, rg, jc, acc);
  __syncthreads();
  #pragma unroll
  for(int i=0;i<4;i++){
    float4 x = make_float4(fmaxf(acc[i][0],0.f), fmaxf(acc[i][1],0.f),
                           fmaxf(acc[i][2],0.f), fmaxf(acc[i][3],0.f));
    *(float4*)&sA[(rg*4+i)*AP + 4*jc] = x;
  }
  init_bias(acc, bl2, jc);
  gemm_phase(sA, sW, Wl2, 128, rg, jc, acc);
  #pragma unroll
  for(int i=0;i<4;i++){
    int n = n0 + rg*4 + i;
    if(n < NNODES){
      float4 x = *(const float4*)&h[(size_t)n*128 + 4*jc];
      x.x += acc[i][0]; x.y += acc[i][1]; x.z += acc[i][2]; x.w += acc[i][3];
      *(float4*)&h[(size_t)n*128 + 4*jc] = x;
    }
  }
}

// ---------- instance-norm stats / norm ----------
__global__ __launch_bounds__(256) void k_stats(const float* h, float* sum, float* sq){
  int col = threadIdx.x & 127, half = threadIdx.x >> 7;
  float s = 0.f, q = 0.f;
  for(int n = blockIdx.x*2 + half; n < NNODES; n += gridDim.x*2){
    float x = h[(size_t)n*128 + col];
    s += x; q += x*x;
  }
  __shared__ float ls[256], lq[256];
  ls[threadIdx.x] = s; lq[threadIdx.x] = q;
  __syncthreads();
  if(half == 0){
    atomicAdd(&sum[col], ls[col] + ls[128+col]);
    atomicAdd(&sq[col],  lq[col] + lq[128+col]);
  }
}

__global__ void k_norm(float* h, const float* sum, const float* sq){
  size_t i = (size_t)blockIdx.x*256 + threadIdx.x;
  if(i < (size_t)NNODES*128){
    int col = i & 127;
    float mean = sum[col] * (1.0f/NNODES);
    float var  = sq[col] * (1.0f/NNODES) - mean*mean;
    if(var < 0.f) var = 0.f;
    h[i] = (h[i] - mean) * rsqrtf(var + 1e-5f);
  }
}

// ---------- output head + epilogue ----------
__global__ __launch_bounds__(256) void k_out(const float* h, const float* pos, const float* v,
    const float* domn, const float* W1, const float* b1, const float* W2, const float* b2,
    float* out){
  __shared__ __align__(16) float sA[32*AP];
  __shared__ __align__(16) float sW[32*128];
  __shared__ float sW2[128*9], sB2[9], sDn[3];
  int t = threadIdx.x, n0 = blockIdx.x*32;
  for(int idx = t; idx < 128*9; idx += 256) sW2[idx] = W2[idx];
  if(t < 9) sB2[t] = b2[t];
  if(t >= 16 && t < 19) sDn[t-16] = domn[t-16];
  for(int idx = t; idx < 1024; idx += 256){
    int row = idx>>5, c4 = (idx&31)*4;
    int n = n0 + row; if(n >= NNODES) n = NNODES-1;
    *(float4*)&sA[row*AP + c4] = *(const float4*)&h[(size_t)n*128 + c4];
  }
  int rg = t>>5, jc = t&31;
  float acc[4][4];
  init_bias(acc, b1, jc);
  gemm_phase(sA, sW, W1, 128, rg, jc, acc);
  __syncthreads();
  #pragma unroll
  for(int i=0;i<4;i++){
    float4 x = make_float4(fmaxf(acc[i][0],0.f), fmaxf(acc[i][1],0.f),
                           fmaxf(acc[i][2],0.f), fmaxf(acc[i][3],0.f));
    *(float4*)&sA[(rg*4+i)*AP + 4*jc] = x;
  }
  __syncthreads();
  for(int idx = t; idx < 32*9; idx += 256){
    int n = idx/9, c = idx%9;
    int gn = n0 + n;
    if(gn < NNODES){
      float s = sB2[c];
      for(int k=0;k<128;k++) s = fmaf(sA[n*AP + k], sW2[k*9 + c], s);
      if(c < 3){
        float p = 0.001f*s + pos[(size_t)gn*3 + c];
        float dn = sDn[c];
        p = p - floorf(p/dn)*dn;
        out[(size_t)gn*3 + c] = p;
      } else {
        float scale = (c < 6) ? 0.001f : 0.01f;
        float p = scale*s + v[(size_t)gn*6 + (c-3)];
        out[(size_t)150000 + (size_t)gn*6 + (c-3)] = p;
      }
    }
  }
}

// ---------- macro head ----------
__global__ __launch_bounds__(128) void k_macro(const float* sum, const float* W1,
    const float* b1, const float* W2, const float* b2, float* out){
  __shared__ float hm[128], t1[128];
  int t = threadIdx.x;
  hm[t] = sum[t] * (1.0f/NNODES);
  __syncthreads();
  float s = b1[t];
  for(int k=0;k<128;k++) s = fmaf(hm[k], W1[(size_t)k*128 + t], s);
  t1[t] = fmaxf(s, 0.0f);
  __syncthreads();
  if(t < 3){
    float o = b2[t];
    for(int k=0;k<128;k++) o = fmaf(t1[k], W2[(size_t)k*3 + t], o);
    out[450000 + t] = o;
  }
}

extern "C" void kernel_launch(void* const* d_in, const int* in_sizes, int n_in,
                              void* d_out, int out_size, void* d_ws, size_t ws_size,
                              hipStream_t stream){
  const float* v    = (const float*)d_in[0];
  const float* pos  = (const float*)d_in[1];
  const float* r    = (const float*)d_in[2];
  const float* dom  = (const float*)d_in[3];
  const float* tt   = (const float*)d_in[4];
  const float* xg   = (const float*)d_in[5];
  const float* domn = (const float*)d_in[6];
  const float* tn   = (const float*)d_in[7];
  const int*   ei   = (const int*)d_in[8];
  const float* embW1=(const float*)d_in[10]; const float* embB1=(const float*)d_in[11];
  const float* embW2=(const float*)d_in[12]; const float* embB2=(const float*)d_in[13];
  const float* msgW1=(const float*)d_in[14]; const float* msgB1=(const float*)d_in[15];
  const float* msgW2=(const float*)d_in[16]; const float* msgB2=(const float*)d_in[17];
  const float* updW1=(const float*)d_in[18]; const float* updB1=(const float*)d_in[19];
  const float* updW2=(const float*)d_in[20]; const float* updB2=(const float*)d_in[21];
  const float* outW1=(const float*)d_in[22]; const float* outB1=(const float*)d_in[23];
  const float* outW2=(const float*)d_in[24]; const float* outB2=(const float*)d_in[25];
  const float* macW1=(const float*)d_in[26]; const float* macB1=(const float*)d_in[27];
  const float* macW2=(const float*)d_in[28]; const float* macB2=(const float*)d_in[29];

  float* ws = (float*)d_ws;
  const bool big    = ws_size >= (size_t)102604288;
  const bool sorted = ws_size >= (size_t)105604292;
  float* h   = ws;                       // N*128
  float* agg = ws + (size_t)6400000;     // N*128
  float* P = 0; float* deg; float* gf; float* sum; float* sq; float* bb1 = 0;
  float* Sb = 0;
  int *cnt=0, *off=0, *cur=0, *srcP=0, *dstP=0;
  if(big){
    P   = ws + (size_t)12800000;         // N*256
    deg = ws + (size_t)25600000;
    Sb  = ws + (size_t)25600000;         // fused tier reuses deg slot
    gf  = ws + (size_t)25650016;
    sum = ws + (size_t)25650048;
    sq  = ws + (size_t)25650176;
    bb1 = ws + (size_t)25650304;
    if(sorted){
      cnt  = (int*)(ws + 25651072);
      off  = (int*)(ws + 25701072);
      cur  = (int*)(ws + 25751073);
      srcP = (int*)(ws + 25801073);
      dstP = (int*)(ws + 26101073);
    }
  } else {
    deg = ws + (size_t)12800000;
    gf  = ws + (size_t)12850000;
    sum = ws + (size_t)12850016;
    sq  = ws + (size_t)12850144;
  }

  float* out = (float*)d_out;

  k_gf<<<1, 64, 0, stream>>>(dom, tt, xg, domn, tn, gf);
  if(big) k_gfb<<<3, 256, 0, stream>>>(gf, msgW1, msgB1, bb1);

  if(sorted){
    // ---- fused 64-row path ----
    hipMemsetAsync(Sb, 0, 7*256*4, stream);
    hipMemsetAsync(agg, 0, (size_t)6400000*4, stream);
    hipMemsetAsync(cnt, 0, (size_t)NNODES*4, stream);
    hipMemsetAsync(cur, 0, (size_t)NNODES*4, stream);
    k_histi<<<(NEDGES+255)/256, 256, 0, stream>>>(ei, cnt);
    k_scan<<<1, 1024, 0, stream>>>(cnt, off);
    k_scatter<<<(NEDGES+255)/256, 256, 0, stream>>>(ei, off, cur, srcP, dstP);
    k_embed<<<(NNODES+31)/32, 256, 0, stream>>>(r, v, gf, embW1, embB1, embW2, embB2, h);
    for(int l = 0; l < NL; l++){
      k_pre2b<<<(NNODES+63)/64, 256, 0, stream>>>(h, msgW1 + (size_t)l*35712, P,
          (l > 0) ? (Sb + (l-1)*256) : Sb, (l > 0) ? 1 : 0);
      k_msg3b<<<(NEDGES+63)/64, 256, 0, stream>>>(srcP, dstP, P, pos, v, r, dom,
          msgW1 + (size_t)l*35712, msgW2 + (size_t)l*16384,
          bb1 + l*128, msgB2 + l*128, agg);
      k_upd2b<<<(NNODES+63)/64, 256, 0, stream>>>(h, agg, cnt, gf,
          updW1 + (size_t)l*34304, updB1 + l*128,
          updW2 + (size_t)l*16384, updB2 + l*128, Sb + l*256);
    }
    k_norm<<<25000, 256, 0, stream>>>(h, Sb + 5*256, Sb + 5*256 + 128);
    k_stats<<<256, 256, 0, stream>>>(h, Sb + 6*256, Sb + 6*256 + 128);
    k_macro<<<1, 128, 0, stream>>>(Sb + 6*256, macW1, macB1, macW2, macB2, out);
    k_out<<<(NNODES+31)/32, 256, 0, stream>>>(h, pos, v, domn,
                                              outW1, outB1, outW2, outB2, out);
    return;
  }

  // ---- fallback paths (round-6 / round-3) ----
  hipMemsetAsync(deg, 0, (size_t)NNODES*4, stream);
  k_deg<<<(NEDGES+255)/256, 256, 0, stream>>>(ei, deg);
  k_embed<<<(NNODES+31)/32, 256, 0, stream>>>(r, v, gf, embW1, embB1, embW2, embB2, h);
  for(int l = 0; l < NL; l++){
    hipMemsetAsync(agg, 0, (size_t)6400000*4, stream);
    if(big){
      k_pre<<<(NNODES+31)/32, 256, 0, stream>>>(h, msgW1 + (size_t)l*35712, P);
      k_msg2<<<NEDGES/32, 256, 0, stream>>>(ei, P, pos, v, r, dom,
          msgW1 + (size_t)l*35712, msgW2 + (size_t)l*16384,
          bb1 + l*128, msgB2 + l*128, agg);
    } else {
      k_msg_old<<<NEDGES/32, 256, 0, stream>>>(ei, h, pos, v, r, dom, gf,
          msgW1, msgB1, msgW2, msgB2, agg, l);
    }
    k_upd<<<(NNODES+31)/32, 256, 0, stream>>>(h, agg, deg, gf,
        updW1, updB1, updW2, updB2, l);
    hipMemsetAsync(sum, 0, 128*4, stream);
    hipMemsetAsync(sq,  0, 128*4, stream);
    k_stats<<<256, 256, 0, stream>>>(h, sum, sq);
    k_norm<<<25000, 256, 0, stream>>>(h, sum, sq);
  }
  hipMemsetAsync(sum, 0, 128*4, stream);
  hipMemsetAsync(sq,  0, 128*4, stream);
  k_stats<<<256, 256, 0, stream>>>(h, sum, sq);
  k_macro<<<1, 128, 0, stream>>>(sum, macW1, macB1, macW2, macB2, out);
  k_out<<<(NNODES+31)/32, 256, 0, stream>>>(h, pos, v, domn,
                                            outW1, outB1, outW2, outB2, out);
}

// Round 13
// 2535.150 us; speedup vs baseline: 1.5989x; 1.5989x over previous
//
#include <hip/hip_runtime.h>
#include <hip/hip_bf16.h>

#define NNODES 50000
#define NEDGES 300000
#define NL 6
#define AP 132   // fp32 A-tile row pitch: 128 + 4 pad

// ---------- tiny setup kernels ----------
__global__ void k_gf(const float* dom, const float* t, const float* xg,
                     const float* domn, const float* tn, float* gf){
  int i = threadIdx.x;
  if(i < 3)        gf[i]  = dom[i];
  else if(i == 3)  gf[3]  = t[0];
  else if(i < 8)   gf[i]  = xg[i-4];
  else if(i < 11)  gf[i]  = domn[i-8];
  else if(i == 11) gf[11] = tn[0];
}

__global__ void k_deg(const int* ei, float* deg){
  int e = blockIdx.x*blockDim.x + threadIdx.x;
  if(e < NEDGES) atomicAdd(&deg[ei[NEDGES + e]], 1.0f);
}

__global__ void k_histi(const int* ei, int* cnt){
  int e = blockIdx.x*blockDim.x + threadIdx.x;
  if(e < NEDGES) atomicAdd(&cnt[ei[NEDGES + e]], 1);
}

// single-block exclusive scan of cnt[NNODES] -> off[NNODES+1]
__global__ __launch_bounds__(1024) void k_scan(const int* cnt, int* off){
  __shared__ int buf[1024];
  __shared__ int carry;
  int t = threadIdx.x;
  if(t == 0) carry = 0;
  __syncthreads();
  for(int base = 0; base < NNODES; base += 1024){
    int i = base + t;
    int x = (i < NNODES) ? cnt[i] : 0;
    buf[t] = x;
    __syncthreads();
    for(int ofs = 1; ofs < 1024; ofs <<= 1){
      int y = (t >= ofs) ? buf[t-ofs] : 0;
      __syncthreads();
      buf[t] += y;
      __syncthreads();
    }
    if(i < NNODES) off[i] = carry + buf[t] - x;
    __syncthreads();
    if(t == 1023) carry += buf[1023];
    __syncthreads();
  }
  if(t == 0) off[NNODES] = carry;
}

// counting-sort scatter: edges grouped by dst
__global__ void k_scatter(const int* ei, const int* off, int* cur, int* srcP, int* dstP){
  int e = blockIdx.x*blockDim.x + threadIdx.x;
  if(e < NEDGES){
    int s = ei[e], d = ei[NEDGES + e];
    int p = atomicAdd(&cur[d], 1);
    int ix = off[d] + p;
    srcP[ix] = s; dstP[ix] = d;
  }
}

// bb1[l][c] = msgB1[l][c] + sum_j gf[j]*msgW1[l][267+j][c]
__global__ void k_gfb(const float* gf, const float* mW1, const float* mB1, float* bb1){
  int i = blockIdx.x*256 + threadIdx.x;
  if(i < 768){
    int l = i >> 7, c = i & 127;
    float s = mB1[l*128 + c];
    #pragma unroll
    for(int j=0;j<12;j++) s = fmaf(gf[j], mW1[(size_t)l*35712 + (size_t)(267+j)*128 + c], s);
    bb1[i] = s;
  }
}

// ---------- shared fp32 GEMM machinery ----------
__device__ __forceinline__ void fill_w(float* sW, const float* gW, int KC){
  for(int idx = threadIdx.x; idx < 32*32; idx += 256){
    int kk = idx >> 5, c4 = (idx & 31)*4;
    float4 w = make_float4(0.f,0.f,0.f,0.f);
    if(kk < KC) w = *(const float4*)(gW + (size_t)kk*128 + c4);
    *(float4*)(sW + kk*128 + c4) = w;
  }
}
__device__ __forceinline__ void gemm_chunk(const float* At, const float* sW,
                                           int KCp, int rg, int jc, float acc[4][4]){
  for(int kkg = 0; kkg < KCp; kkg += 4){
    float4 av[4];
    #pragma unroll
    for(int i=0;i<4;i++) av[i] = *(const float4*)(At + (rg*4+i)*AP + kkg);
    #pragma unroll
    for(int q=0;q<4;q++){
      float4 bq = *(const float4*)(sW + (kkg+q)*128 + 4*jc);
      #pragma unroll
      for(int i=0;i<4;i++){
        float aa = ((const float*)&av[i])[q];
        acc[i][0] = fmaf(aa, bq.x, acc[i][0]);
        acc[i][1] = fmaf(aa, bq.y, acc[i][1]);
        acc[i][2] = fmaf(aa, bq.z, acc[i][2]);
        acc[i][3] = fmaf(aa, bq.w, acc[i][3]);
      }
    }
  }
}
__device__ __forceinline__ void gemm_phase(const float* sA, float* sW, const float* gW,
                                           int K, int rg, int jc, float acc[4][4]){
  for(int k0 = 0; k0 < K; k0 += 32){
    int KC = (K - k0 < 32) ? (K - k0) : 32;
    __syncthreads();
    fill_w(sW, gW + (size_t)k0*128, KC);
    __syncthreads();
    gemm_chunk(sA + k0, sW, (KC+3)&~3, rg, jc, acc);
  }
}
__device__ __forceinline__ void init_bias(float acc[4][4], const float* b, int jc){
  float4 bb = *(const float4*)(b + 4*jc);
  #pragma unroll
  for(int i=0;i<4;i++){ acc[i][0]=bb.x; acc[i][1]=bb.y; acc[i][2]=bb.z; acc[i][3]=bb.w; }
}

// ---------- embedding ----------
__global__ __launch_bounds__(256) void k_embed(const float* r, const float* v, const float* gf,
    const float* W1, const float* b1, const float* W2, const float* b2, float* h){
  __shared__ __align__(16) float sA[32*AP];
  __shared__ __align__(16) float sW[32*128];
  __shared__ float sGf[12];
  int t = threadIdx.x, n0 = blockIdx.x*32;
  if(t < 12) sGf[t] = gf[t];
  __syncthreads();
  for(int idx = t; idx < 32*20; idx += 256){
    int row = idx/20, c = idx%20;
    int n = n0 + row; if(n >= NNODES) n = NNODES-1;
    float val;
    if(c == 0)      val = r[n];
    else if(c < 7)  val = v[(size_t)n*6 + (c-1)];
    else if(c < 19) val = sGf[c-7];
    else            val = 0.0f;
    sA[row*AP + c] = val;
  }
  int rg = t>>5, jc = t&31;
  float acc[4][4];
  init_bias(acc, b1, jc);
  gemm_phase(sA, sW, W1, 19, rg, jc, acc);
  __syncthreads();
  #pragma unroll
  for(int i=0;i<4;i++){
    float4 x = make_float4(fmaxf(acc[i][0],0.f), fmaxf(acc[i][1],0.f),
                           fmaxf(acc[i][2],0.f), fmaxf(acc[i][3],0.f));
    *(float4*)&sA[(rg*4+i)*AP + 4*jc] = x;
  }
  init_bias(acc, b2, jc);
  gemm_phase(sA, sW, W2, 128, rg, jc, acc);
  #pragma unroll
  for(int i=0;i<4;i++){
    int n = n0 + rg*4 + i;
    if(n < NNODES){
      float4 x = make_float4(fmaxf(acc[i][0],0.f), fmaxf(acc[i][1],0.f),
                             fmaxf(acc[i][2],0.f), fmaxf(acc[i][3],0.f));
      *(float4*)&h[(size_t)n*128 + 4*jc] = x;
    }
  }
}

// ---------- fused: [instance-norm from prev-layer stats] + P precompute ----------
__global__ __launch_bounds__(256) void k_pre2(float* h, const float* W1, float* P,
                                              const float* S, int doNorm){
  __shared__ __align__(16) float sA[32*AP];
  __shared__ __align__(16) float sW[32*128];
  __shared__ float sMu[128], sIv[128];
  int t = threadIdx.x, n0 = blockIdx.x*32;
  if(doNorm){
    if(t < 128){
      float mean = S[t] * (1.0f/NNODES);
      float var  = S[128+t] * (1.0f/NNODES) - mean*mean;
      if(var < 0.f) var = 0.f;
      sMu[t] = mean; sIv[t] = rsqrtf(var + 1e-5f);
    }
    __syncthreads();
    for(int idx = t; idx < 1024; idx += 256){
      int row = idx>>5, c4 = (idx&31)*4;
      int n = n0 + row; bool valid = (n < NNODES); if(!valid) n = NNODES-1;
      float4 x = *(const float4*)&h[(size_t)n*128 + c4];
      x.x = (x.x - sMu[c4+0])*sIv[c4+0];
      x.y = (x.y - sMu[c4+1])*sIv[c4+1];
      x.z = (x.z - sMu[c4+2])*sIv[c4+2];
      x.w = (x.w - sMu[c4+3])*sIv[c4+3];
      *(float4*)&sA[row*AP + c4] = x;
      if(valid) *(float4*)&h[(size_t)n*128 + c4] = x;  // persist normalized h
    }
  } else {
    for(int idx = t; idx < 1024; idx += 256){
      int row = idx>>5, c4 = (idx&31)*4;
      int n = n0 + row; if(n >= NNODES) n = NNODES-1;
      *(float4*)&sA[row*AP + c4] = *(const float4*)&h[(size_t)n*128 + c4];
    }
  }
  int rg = t>>5, jc = t&31;
  float acc[4][4];
  #pragma unroll
  for(int i=0;i<4;i++){ acc[i][0]=0.f; acc[i][1]=0.f; acc[i][2]=0.f; acc[i][3]=0.f; }
  gemm_phase(sA, sW, W1, 128, rg, jc, acc);               // W1a
  #pragma unroll
  for(int i=0;i<4;i++){
    int n = n0 + rg*4 + i;
    if(n < NNODES)
      *(float4*)&P[(size_t)n*256 + 4*jc] = make_float4(acc[i][0],acc[i][1],acc[i][2],acc[i][3]);
  }
  #pragma unroll
  for(int i=0;i<4;i++){ acc[i][0]=0.f; acc[i][1]=0.f; acc[i][2]=0.f; acc[i][3]=0.f; }
  gemm_phase(sA, sW, W1 + (size_t)128*128, 128, rg, jc, acc);  // W1b
  #pragma unroll
  for(int i=0;i<4;i++){
    int n = n0 + rg*4 + i;
    if(n < NNODES)
      *(float4*)&P[(size_t)n*256 + 128 + 4*jc] = make_float4(acc[i][0],acc[i][1],acc[i][2],acc[i][3]);
  }
}

// ---------- edge kernel: dst-sorted, z1 direct into registers, segment-reduced ----------
__global__ __launch_bounds__(256) void k_msg3(const int* srcP, const int* dstP, const float* P,
    const float* pos, const float* v, const float* r, const float* dom,
    const float* W1, const float* W2, const float* bb1, const float* b2, float* agg){
  __shared__ __align__(16) float sM[32*AP];
  __shared__ __align__(16) float sW[32*128];
  __shared__ float sT[32*12];
  __shared__ float sB[128];
  __shared__ int sSrc[32], sDst[32];
  int t = threadIdx.x, e0 = blockIdx.x*32;   // NEDGES = 32*9375 exactly
  if(t < 32){ sSrc[t] = srcP[e0+t]; sDst[t] = dstP[e0+t]; }
  if(t >= 128) sB[t-128] = bb1[t-128];
  __syncthreads();            // indices + sB visible
  // W1c rows 0..10 into sW
  for(int idx = t; idx < 352; idx += 256){
    int kk = idx>>5, c4 = (idx&31)*4;
    *(float4*)&sW[kk*128 + c4] = *(const float4*)&W1[(size_t)(256+kk)*128 + c4];
  }
  // tail: dpos(3), dv(6), r_dst, r_src
  if(t < 32){
    int s = sSrc[t], d = sDst[t];
    #pragma unroll
    for(int c=0;c<3;c++){
      float dp = pos[(size_t)d*3+c] - pos[(size_t)s*3+c];
      float dm = dom[c];
      dp = dp - dm * rintf(dp/dm);
      sT[t*12 + c] = dp;
    }
    #pragma unroll
    for(int c=0;c<6;c++)
      sT[t*12 + 3 + c] = v[(size_t)d*6+c] - v[(size_t)s*6+c];
    sT[t*12 + 9]  = r[d];
    sT[t*12 + 10] = r[s];
    sT[t*12 + 11] = 0.0f;
  }
  int rg = t>>5, jc = t&31;
  // z1 directly into acc: rows rg*4+i, cols 4jc..4jc+3 (per row-group: 32 lanes
  // read contiguous 512B from P — coalesced; skips LDS round-trip + 1 barrier)
  float acc[4][4];
  {
    float4 bb = *(const float4*)&sB[4*jc];
    #pragma unroll
    for(int i=0;i<4;i++){
      int row = rg*4 + i;
      float4 pd = *(const float4*)&P[(size_t)sDst[row]*256 + 4*jc];
      float4 ps = *(const float4*)&P[(size_t)sSrc[row]*256 + 128 + 4*jc];
      acc[i][0] = bb.x + pd.x + ps.x;
      acc[i][1] = bb.y + pd.y + ps.y;
      acc[i][2] = bb.z + pd.z + ps.z;
      acc[i][3] = bb.w + pd.w + ps.w;
    }
  }
  __syncthreads();            // sW (W1c) + sT visible
  for(int k=0;k<11;k++){
    float4 b = *(const float4*)&sW[k*128 + 4*jc];
    #pragma unroll
    for(int i=0;i<4;i++){
      float a = sT[(rg*4+i)*12 + k];
      acc[i][0] = fmaf(a, b.x, acc[i][0]);
      acc[i][1] = fmaf(a, b.y, acc[i][1]);
      acc[i][2] = fmaf(a, b.z, acc[i][2]);
      acc[i][3] = fmaf(a, b.w, acc[i][3]);
    }
  }
  // relu -> hidden in sM (each thread owns its cells)
  #pragma unroll
  for(int i=0;i<4;i++){
    float4 x = make_float4(fmaxf(acc[i][0],0.f), fmaxf(acc[i][1],0.f),
                           fmaxf(acc[i][2],0.f), fmaxf(acc[i][3],0.f));
    *(float4*)&sM[(rg*4+i)*AP + 4*jc] = x;
  }
  // MLP2 (K=128); gemm_phase's leading barrier protects sM/sW reuse
  init_bias(acc, b2, jc);
  gemm_phase(sM, sW, W2, 128, rg, jc, acc);
  __syncthreads();
  #pragma unroll
  for(int i=0;i<4;i++){
    float4 x = make_float4(fmaxf(acc[i][0],0.f), fmaxf(acc[i][1],0.f),
                           fmaxf(acc[i][2],0.f), fmaxf(acc[i][3],0.f));
    *(float4*)&sM[(rg*4+i)*AP + 4*jc] = x;
  }
  __syncthreads();
  // segment reduce: 128 threads/half, 16 rows each
  int col = t & 127, half = t >> 7;
  int rbeg = half*16, rend = rbeg + 16;
  int cur = sDst[rbeg];
  float run = 0.f;
  for(int row = rbeg; row < rend; row++){
    run += sM[row*AP + col];
    int nxt = (row+1 < rend) ? sDst[row+1] : -1;
    if(nxt != cur){
      atomicAdd(&agg[(size_t)cur*128 + col], run);
      run = 0.f; cur = nxt;
    }
  }
}

// ---------- fused node update: h += MLP([h, agg/deg, gf]); zeros agg; stats -> S ----------
__global__ __launch_bounds__(256) void k_upd2(float* h, float* agg, const int* cnt,
    const float* gf, const float* W1, const float* b1, const float* W2, const float* b2,
    float* S){
  __shared__ __align__(16) float sA[32*AP];
  __shared__ __align__(16) float sW[32*128];
  __shared__ float pS[8*128], pQ[8*128];
  __shared__ float sGf[12], sRd[32];
  int t = threadIdx.x, n0 = blockIdx.x*32;
  if(t < 12) sGf[t] = gf[t];
  if(t < 32){
    int n = n0 + t; if(n >= NNODES) n = NNODES-1;
    sRd[t] = 1.0f / fmaxf((float)cnt[n], 1.0f);
  }
  __syncthreads();
  int rg = t>>5, jc = t&31;
  float acc[4][4];
  init_bias(acc, b1, jc);
  for(int idx = t; idx < 1024; idx += 256){
    int row = idx>>5, c4 = (idx&31)*4;
    int n = n0 + row; if(n >= NNODES) n = NNODES-1;
    *(float4*)&sA[row*AP + c4] = *(const float4*)&h[(size_t)n*128 + c4];
  }
  gemm_phase(sA, sW, W1, 128, rg, jc, acc);
  __syncthreads();
  for(int idx = t; idx < 1024; idx += 256){
    int row = idx>>5, c4 = (idx&31)*4;
    int n = n0 + row; bool valid = (n < NNODES); if(!valid) n = NNODES-1;
    float4 x = *(const float4*)&agg[(size_t)n*128 + c4];
    float rd = sRd[row];
    x.x*=rd; x.y*=rd; x.z*=rd; x.w*=rd;
    *(float4*)&sA[row*AP + c4] = x;
    if(valid) *(float4*)&agg[(size_t)n*128 + c4] = make_float4(0.f,0.f,0.f,0.f);
  }
  gemm_phase(sA, sW, W1 + (size_t)128*128, 128, rg, jc, acc);
  __syncthreads();
  if(t < 32){
    #pragma unroll
    for(int c=0;c<12;c++) sA[t*AP + c] = sGf[c];
  }
  gemm_phase(sA, sW, W1 + (size_t)256*128, 12, rg, jc, acc);
  __syncthreads();
  #pragma unroll
  for(int i=0;i<4;i++){
    float4 x = make_float4(fmaxf(acc[i][0],0.f), fmaxf(acc[i][1],0.f),
                           fmaxf(acc[i][2],0.f), fmaxf(acc[i][3],0.f));
    *(float4*)&sA[(rg*4+i)*AP + 4*jc] = x;
  }
  init_bias(acc, b2, jc);
  gemm_phase(sA, sW, W2, 128, rg, jc, acc);   // no relu
  float sc[4] = {0.f,0.f,0.f,0.f}, qc[4] = {0.f,0.f,0.f,0.f};
  #pragma unroll
  for(int i=0;i<4;i++){
    int n = n0 + rg*4 + i;
    if(n < NNODES){
      float4 x = *(const float4*)&h[(size_t)n*128 + 4*jc];
      x.x += acc[i][0]; x.y += acc[i][1]; x.z += acc[i][2]; x.w += acc[i][3];
      *(float4*)&h[(size_t)n*128 + 4*jc] = x;
      sc[0]+=x.x; sc[1]+=x.y; sc[2]+=x.z; sc[3]+=x.w;
      qc[0]+=x.x*x.x; qc[1]+=x.y*x.y; qc[2]+=x.z*x.z; qc[3]+=x.w*x.w;
    }
  }
  #pragma unroll
  for(int c=0;c<4;c++){ pS[rg*128 + 4*jc + c] = sc[c]; pQ[rg*128 + 4*jc + c] = qc[c]; }
  __syncthreads();
  if(t < 128){
    float s = 0.f, q = 0.f;
    #pragma unroll
    for(int g=0; g<8; g++){ s += pS[g*128 + t]; q += pQ[g*128 + t]; }
    atomicAdd(&S[t], s);
    atomicAdd(&S[128 + t], q);
  }
}

// ---------- fallback kernels (round-6 / round-3 tiers, verbatim) ----------
__global__ __launch_bounds__(256) void k_msg2(const int* ei, const float* P,
    const float* pos, const float* v, const float* r, const float* dom,
    const float* W1, const float* W2, const float* bb1, const float* b2, float* agg){
  __shared__ __align__(16) float sM[32*AP];
  __shared__ __align__(16) float sW[32*128];
  __shared__ float sT[32*12];
  __shared__ float sB[128];
  __shared__ int sSrc[32], sDst[32];
  int t = threadIdx.x, e0 = blockIdx.x*32;
  if(t < 32){ sSrc[t] = ei[e0+t]; sDst[t] = ei[NEDGES + e0 + t]; }
  if(t >= 128) sB[t-128] = bb1[t-128];
  __syncthreads();
  for(int idx = t; idx < 352; idx += 256){
    int kk = idx>>5, c4 = (idx&31)*4;
    *(float4*)&sW[kk*128 + c4] = *(const float4*)&W1[(size_t)(256+kk)*128 + c4];
  }
  if(t < 32){
    int s = sSrc[t], d = sDst[t];
    #pragma unroll
    for(int c=0;c<3;c++){
      float dp = pos[(size_t)d*3+c] - pos[(size_t)s*3+c];
      float dm = dom[c];
      dp = dp - dm * rintf(dp/dm);
      sT[t*12 + c] = dp;
    }
    #pragma unroll
    for(int c=0;c<6;c++)
      sT[t*12 + 3 + c] = v[(size_t)d*6+c] - v[(size_t)s*6+c];
    sT[t*12 + 9]  = r[d];
    sT[t*12 + 10] = r[s];
    sT[t*12 + 11] = 0.0f;
  }
  for(int idx = t; idx < 1024; idx += 256){
    int row = idx>>5, c4 = (idx&31)*4;
    float4 pd = *(const float4*)&P[(size_t)sDst[row]*256 + c4];
    float4 ps = *(const float4*)&P[(size_t)sSrc[row]*256 + 128 + c4];
    float4 bb = *(const float4*)&sB[c4];
    *(float4*)&sM[row*AP + c4] = make_float4(bb.x+pd.x+ps.x, bb.y+pd.y+ps.y,
                                             bb.z+pd.z+ps.z, bb.w+pd.w+ps.w);
  }
  __syncthreads();
  int rg = t>>5, jc = t&31;
  float acc[4][4];
  #pragma unroll
  for(int i=0;i<4;i++)
    #pragma unroll
    for(int c=0;c<4;c++) acc[i][c] = sM[(rg*4+i)*AP + 4*jc + c];
  for(int k=0;k<11;k++){
    float4 b = *(const float4*)&sW[k*128 + 4*jc];
    #pragma unroll
    for(int i=0;i<4;i++){
      float a = sT[(rg*4+i)*12 + k];
      acc[i][0] = fmaf(a, b.x, acc[i][0]);
      acc[i][1] = fmaf(a, b.y, acc[i][1]);
      acc[i][2] = fmaf(a, b.z, acc[i][2]);
      acc[i][3] = fmaf(a, b.w, acc[i][3]);
    }
  }
  #pragma unroll
  for(int i=0;i<4;i++){
    float4 x = make_float4(fmaxf(acc[i][0],0.f), fmaxf(acc[i][1],0.f),
                           fmaxf(acc[i][2],0.f), fmaxf(acc[i][3],0.f));
    *(float4*)&sM[(rg*4+i)*AP + 4*jc] = x;
  }
  init_bias(acc, b2, jc);
  gemm_phase(sM, sW, W2, 128, rg, jc, acc);
  #pragma unroll
  for(int i=0;i<4;i++){
    int d = sDst[rg*4+i];
    #pragma unroll
    for(int c=0;c<4;c++)
      atomicAdd(&agg[(size_t)d*128 + 4*jc + c], fmaxf(acc[i][c], 0.0f));
  }
}

__global__ __launch_bounds__(256) void k_pre(const float* h, const float* W1, float* P){
  __shared__ __align__(16) float sA[32*AP];
  __shared__ __align__(16) float sW[32*128];
  int t = threadIdx.x, n0 = blockIdx.x*32;
  for(int idx = t; idx < 1024; idx += 256){
    int row = idx>>5, c4 = (idx&31)*4;
    int n = n0 + row; if(n >= NNODES) n = NNODES-1;
    *(float4*)&sA[row*AP + c4] = *(const float4*)&h[(size_t)n*128 + c4];
  }
  int rg = t>>5, jc = t&31;
  float acc[4][4];
  #pragma unroll
  for(int i=0;i<4;i++){ acc[i][0]=0.f; acc[i][1]=0.f; acc[i][2]=0.f; acc[i][3]=0.f; }
  gemm_phase(sA, sW, W1, 128, rg, jc, acc);
  #pragma unroll
  for(int i=0;i<4;i++){
    int n = n0 + rg*4 + i;
    if(n < NNODES)
      *(float4*)&P[(size_t)n*256 + 4*jc] = make_float4(acc[i][0],acc[i][1],acc[i][2],acc[i][3]);
  }
  #pragma unroll
  for(int i=0;i<4;i++){ acc[i][0]=0.f; acc[i][1]=0.f; acc[i][2]=0.f; acc[i][3]=0.f; }
  gemm_phase(sA, sW, W1 + (size_t)128*128, 128, rg, jc, acc);
  #pragma unroll
  for(int i=0;i<4;i++){
    int n = n0 + rg*4 + i;
    if(n < NNODES)
      *(float4*)&P[(size_t)n*256 + 128 + 4*jc] = make_float4(acc[i][0],acc[i][1],acc[i][2],acc[i][3]);
  }
}

__global__ __launch_bounds__(256) void k_msg_old(const int* ei, const float* h,
    const float* pos, const float* v, const float* r, const float* dom, const float* gf,
    const float* W1, const float* b1, const float* W2, const float* b2, float* agg, int l){
  __shared__ __align__(16) float sA[32*AP];
  __shared__ __align__(16) float sW[32*128];
  __shared__ int sSrc[32], sDst[32];
  __shared__ float sGf[12];
  int t = threadIdx.x, e0 = blockIdx.x*32;
  if(t < 32){ sSrc[t] = ei[e0+t]; sDst[t] = ei[NEDGES + e0 + t]; }
  if(t >= 32 && t < 44) sGf[t-32] = gf[t-32];
  __syncthreads();
  const float* Wl1 = W1 + (size_t)l*35712;
  const float* Wl2 = W2 + (size_t)l*16384;
  const float* bl1 = b1 + l*128;
  const float* bl2 = b2 + l*128;
  int rg = t>>5, jc = t&31;
  float acc[4][4];
  init_bias(acc, bl1, jc);
  for(int idx = t; idx < 1024; idx += 256){
    int row = idx>>5, c4 = (idx&31)*4;
    *(float4*)&sA[row*AP + c4] = *(const float4*)&h[(size_t)sDst[row]*128 + c4];
  }
  gemm_phase(sA, sW, Wl1, 128, rg, jc, acc);
  __syncthreads();
  for(int idx = t; idx < 1024; idx += 256){
    int row = idx>>5, c4 = (idx&31)*4;
    *(float4*)&sA[row*AP + c4] = *(const float4*)&h[(size_t)sSrc[row]*128 + c4];
  }
  gemm_phase(sA, sW, Wl1 + (size_t)128*128, 128, rg, jc, acc);
  __syncthreads();
  if(t < 32){
    int s = sSrc[t], d = sDst[t];
    #pragma unroll
    for(int c=0;c<3;c++){
      float dp = pos[(size_t)d*3+c] - pos[(size_t)s*3+c];
      float dm = dom[c];
      dp = dp - dm * rintf(dp/dm);
      sA[t*AP + c] = dp;
    }
    #pragma unroll
    for(int c=0;c<6;c++)
      sA[t*AP + 3 + c] = v[(size_t)d*6+c] - v[(size_t)s*6+c];
    sA[t*AP + 9]  = r[d];
    sA[t*AP + 10] = r[s];
    #pragma unroll
    for(int c=0;c<12;c++) sA[t*AP + 11 + c] = sGf[c];
    sA[t*AP + 23] = 0.0f;
  }
  gemm_phase(sA, sW, Wl1 + (size_t)256*128, 23, rg, jc, acc);
  __syncthreads();
  #pragma unroll
  for(int i=0;i<4;i++){
    float4 x = make_float4(fmaxf(acc[i][0],0.f), fmaxf(acc[i][1],0.f),
                           fmaxf(acc[i][2],0.f), fmaxf(acc[i][3],0.f));
    *(float4*)&sA[(rg*4+i)*AP + 4*jc] = x;
  }
  init_bias(acc, bl2, jc);
  gemm_phase(sA, sW, Wl2, 128, rg, jc, acc);
  #pragma unroll
  for(int i=0;i<4;i++){
    int d = sDst[rg*4+i];
    #pragma unroll
    for(int c=0;c<4;c++)
      atomicAdd(&agg[(size_t)d*128 + 4*jc + c], fmaxf(acc[i][c], 0.0f));
  }
}

__global__ __launch_bounds__(256) void k_upd(float* h, const float* agg, const float* deg,
    const float* gf, const float* W1, const float* b1, const float* W2, const float* b2, int l){
  __shared__ __align__(16) float sA[32*AP];
  __shared__ __align__(16) float sW[32*128];
  __shared__ float sGf[12], sRd[32];
  int t = threadIdx.x, n0 = blockIdx.x*32;
  if(t < 12) sGf[t] = gf[t];
  if(t < 32){
    int n = n0 + t; if(n >= NNODES) n = NNODES-1;
    sRd[t] = 1.0f / fmaxf(deg[n], 1.0f);
  }
  __syncthreads();
  const float* Wl1 = W1 + (size_t)l*34304;
  const float* Wl2 = W2 + (size_t)l*16384;
  const float* bl1 = b1 + l*128;
  const float* bl2 = b2 + l*128;
  int rg = t>>5, jc = t&31;
  float acc[4][4];
  init_bias(acc, bl1, jc);
  for(int idx = t; idx < 1024; idx += 256){
    int row = idx>>5, c4 = (idx&31)*4;
    int n = n0 + row; if(n >= NNODES) n = NNODES-1;
    *(float4*)&sA[row*AP + c4] = *(const float4*)&h[(size_t)n*128 + c4];
  }
  gemm_phase(sA, sW, Wl1, 128, rg, jc, acc);
  __syncthreads();
  for(int idx = t; idx < 1024; idx += 256){
    int row = idx>>5, c4 = (idx&31)*4;
    int n = n0 + row; if(n >= NNODES) n = NNODES-1;
    float4 x = *(const float4*)&agg[(size_t)n*128 + c4];
    float rd = sRd[row];
    x.x*=rd; x.y*=rd; x.z*=rd; x.w*=rd;
    *(float4*)&sA[row*AP + c4] = x;
  }
  gemm_phase(sA, sW, Wl1 + (size_t)128*128, 128, rg, jc, acc);
  __syncthreads();
  if(t < 32){
    #pragma unroll
    for(int c=0;c<12;c++) sA[t*AP + c] = sGf[c];
  }
  gemm_phase(sA, sW, Wl1 + (size_t)256*128, 12, rg, jc, acc);
  __syncthreads();
  #pragma unroll
  for(int i=0;i<4;i++){
    float4 x = make_float4(fmaxf(acc[i][0],0.f), fmaxf(acc[i][1],0.f),
                           fmaxf(acc[i][2],0.f), fmaxf(acc[i][3],0.f));
    *(float4*)&sA[(rg*4+i)*AP + 4*jc] = x;
  }
  init_bias(acc, bl2, jc);
  gemm_phase(sA, sW, Wl2, 128, rg, jc, acc);
  #pragma unroll
  for(int i=0;i<4;i++){
    int n = n0 + rg*4 + i;
    if(n < NNODES){
      float4 x = *(const float4*)&h[(size_t)n*128 + 4*jc];
      x.x += acc[i][0]; x.y += acc[i][1]; x.z += acc[i][2]; x.w += acc[i][3];
      *(float4*)&h[(size_t)n*128 + 4*jc] = x;
    }
  }
}

// ---------- instance-norm stats / norm ----------
__global__ __launch_bounds__(256) void k_stats(const float* h, float* sum, float* sq){
  int col = threadIdx.x & 127, half = threadIdx.x >> 7;
  float s = 0.f, q = 0.f;
  for(int n = blockIdx.x*2 + half; n < NNODES; n += gridDim.x*2){
    float x = h[(size_t)n*128 + col];
    s += x; q += x*x;
  }
  __shared__ float ls[256], lq[256];
  ls[threadIdx.x] = s; lq[threadIdx.x] = q;
  __syncthreads();
  if(half == 0){
    atomicAdd(&sum[col], ls[col] + ls[128+col]);
    atomicAdd(&sq[col],  lq[col] + lq[128+col]);
  }
}

__global__ void k_norm(float* h, const float* sum, const float* sq){
  size_t i = (size_t)blockIdx.x*256 + threadIdx.x;
  if(i < (size_t)NNODES*128){
    int col = i & 127;
    float mean = sum[col] * (1.0f/NNODES);
    float var  = sq[col] * (1.0f/NNODES) - mean*mean;
    if(var < 0.f) var = 0.f;
    h[i] = (h[i] - mean) * rsqrtf(var + 1e-5f);
  }
}

// ---------- output head + epilogue ----------
__global__ __launch_bounds__(256) void k_out(const float* h, const float* pos, const float* v,
    const float* domn, const float* W1, const float* b1, const float* W2, const float* b2,
    float* out){
  __shared__ __align__(16) float sA[32*AP];
  __shared__ __align__(16) float sW[32*128];
  __shared__ float sW2[128*9], sB2[9], sDn[3];
  int t = threadIdx.x, n0 = blockIdx.x*32;
  for(int idx = t; idx < 128*9; idx += 256) sW2[idx] = W2[idx];
  if(t < 9) sB2[t] = b2[t];
  if(t >= 16 && t < 19) sDn[t-16] = domn[t-16];
  for(int idx = t; idx < 1024; idx += 256){
    int row = idx>>5, c4 = (idx&31)*4;
    int n = n0 + row; if(n >= NNODES) n = NNODES-1;
    *(float4*)&sA[row*AP + c4] = *(const float4*)&h[(size_t)n*128 + c4];
  }
  int rg = t>>5, jc = t&31;
  float acc[4][4];
  init_bias(acc, b1, jc);
  gemm_phase(sA, sW, W1, 128, rg, jc, acc);
  __syncthreads();
  #pragma unroll
  for(int i=0;i<4;i++){
    float4 x = make_float4(fmaxf(acc[i][0],0.f), fmaxf(acc[i][1],0.f),
                           fmaxf(acc[i][2],0.f), fmaxf(acc[i][3],0.f));
    *(float4*)&sA[(rg*4+i)*AP + 4*jc] = x;
  }
  __syncthreads();
  for(int idx = t; idx < 32*9; idx += 256){
    int n = idx/9, c = idx%9;
    int gn = n0 + n;
    if(gn < NNODES){
      float s = sB2[c];
      for(int k=0;k<128;k++) s = fmaf(sA[n*AP + k], sW2[k*9 + c], s);
      if(c < 3){
        float p = 0.001f*s + pos[(size_t)gn*3 + c];
        float dn = sDn[c];
        p = p - floorf(p/dn)*dn;
        out[(size_t)gn*3 + c] = p;
      } else {
        float scale = (c < 6) ? 0.001f : 0.01f;
        float p = scale*s + v[(size_t)gn*6 + (c-3)];
        out[(size_t)150000 + (size_t)gn*6 + (c-3)] = p;
      }
    }
  }
}

// ---------- macro head ----------
__global__ __launch_bounds__(128) void k_macro(const float* sum, const float* W1,
    const float* b1, const float* W2, const float* b2, float* out){
  __shared__ float hm[128], t1[128];
  int t = threadIdx.x;
  hm[t] = sum[t] * (1.0f/NNODES);
  __syncthreads();
  float s = b1[t];
  for(int k=0;k<128;k++) s = fmaf(hm[k], W1[(size_t)k*128 + t], s);
  t1[t] = fmaxf(s, 0.0f);
  __syncthreads();
  if(t < 3){
    float o = b2[t];
    for(int k=0;k<128;k++) o = fmaf(t1[k], W2[(size_t)k*3 + t], o);
    out[450000 + t] = o;
  }
}

extern "C" void kernel_launch(void* const* d_in, const int* in_sizes, int n_in,
                              void* d_out, int out_size, void* d_ws, size_t ws_size,
                              hipStream_t stream){
  const float* v    = (const float*)d_in[0];
  const float* pos  = (const float*)d_in[1];
  const float* r    = (const float*)d_in[2];
  const float* dom  = (const float*)d_in[3];
  const float* tt   = (const float*)d_in[4];
  const float* xg   = (const float*)d_in[5];
  const float* domn = (const float*)d_in[6];
  const float* tn   = (const float*)d_in[7];
  const int*   ei   = (const int*)d_in[8];
  const float* embW1=(const float*)d_in[10]; const float* embB1=(const float*)d_in[11];
  const float* embW2=(const float*)d_in[12]; const float* embB2=(const float*)d_in[13];
  const float* msgW1=(const float*)d_in[14]; const float* msgB1=(const float*)d_in[15];
  const float* msgW2=(const float*)d_in[16]; const float* msgB2=(const float*)d_in[17];
  const float* updW1=(const float*)d_in[18]; const float* updB1=(const float*)d_in[19];
  const float* updW2=(const float*)d_in[20]; const float* updB2=(const float*)d_in[21];
  const float* outW1=(const float*)d_in[22]; const float* outB1=(const float*)d_in[23];
  const float* outW2=(const float*)d_in[24]; const float* outB2=(const float*)d_in[25];
  const float* macW1=(const float*)d_in[26]; const float* macB1=(const float*)d_in[27];
  const float* macW2=(const float*)d_in[28]; const float* macB2=(const float*)d_in[29];

  float* ws = (float*)d_ws;
  const bool big    = ws_size >= (size_t)102604288;
  const bool sorted = ws_size >= (size_t)105604292;
  float* h   = ws;                       // N*128
  float* agg = ws + (size_t)6400000;     // N*128
  float* P = 0; float* deg; float* gf; float* sum; float* sq; float* bb1 = 0;
  float* Sb = 0;
  int *cnt=0, *off=0, *cur=0, *srcP=0, *dstP=0;
  if(big){
    P   = ws + (size_t)12800000;         // N*256
    deg = ws + (size_t)25600000;
    Sb  = ws + (size_t)25600000;         // fused tier reuses deg slot
    gf  = ws + (size_t)25650016;
    sum = ws + (size_t)25650048;
    sq  = ws + (size_t)25650176;
    bb1 = ws + (size_t)25650304;
    if(sorted){
      cnt  = (int*)(ws + 25651072);
      off  = (int*)(ws + 25701072);
      cur  = (int*)(ws + 25751073);
      srcP = (int*)(ws + 25801073);
      dstP = (int*)(ws + 26101073);
    }
  } else {
    deg = ws + (size_t)12800000;
    gf  = ws + (size_t)12850000;
    sum = ws + (size_t)12850016;
    sq  = ws + (size_t)12850144;
  }

  float* out = (float*)d_out;

  k_gf<<<1, 64, 0, stream>>>(dom, tt, xg, domn, tn, gf);
  if(big) k_gfb<<<3, 256, 0, stream>>>(gf, msgW1, msgB1, bb1);

  if(sorted){
    // ---- fused path (round-9 structure; k_msg3 z1-in-registers) ----
    hipMemsetAsync(Sb, 0, 7*256*4, stream);
    hipMemsetAsync(agg, 0, (size_t)6400000*4, stream);
    hipMemsetAsync(cnt, 0, (size_t)NNODES*4, stream);
    hipMemsetAsync(cur, 0, (size_t)NNODES*4, stream);
    k_histi<<<(NEDGES+255)/256, 256, 0, stream>>>(ei, cnt);
    k_scan<<<1, 1024, 0, stream>>>(cnt, off);
    k_scatter<<<(NEDGES+255)/256, 256, 0, stream>>>(ei, off, cur, srcP, dstP);
    k_embed<<<(NNODES+31)/32, 256, 0, stream>>>(r, v, gf, embW1, embB1, embW2, embB2, h);
    for(int l = 0; l < NL; l++){
      k_pre2<<<(NNODES+31)/32, 256, 0, stream>>>(h, msgW1 + (size_t)l*35712, P,
          (l > 0) ? (Sb + (l-1)*256) : Sb, (l > 0) ? 1 : 0);
      k_msg3<<<NEDGES/32, 256, 0, stream>>>(srcP, dstP, P, pos, v, r, dom,
          msgW1 + (size_t)l*35712, msgW2 + (size_t)l*16384,
          bb1 + l*128, msgB2 + l*128, agg);
      k_upd2<<<(NNODES+31)/32, 256, 0, stream>>>(h, agg, cnt, gf,
          updW1 + (size_t)l*34304, updB1 + l*128,
          updW2 + (size_t)l*16384, updB2 + l*128, Sb + l*256);
    }
    k_norm<<<25000, 256, 0, stream>>>(h, Sb + 5*256, Sb + 5*256 + 128);
    k_stats<<<256, 256, 0, stream>>>(h, Sb + 6*256, Sb + 6*256 + 128);
    k_macro<<<1, 128, 0, stream>>>(Sb + 6*256, macW1, macB1, macW2, macB2, out);
    k_out<<<(NNODES+31)/32, 256, 0, stream>>>(h, pos, v, domn,
                                              outW1, outB1, outW2, outB2, out);
    return;
  }

  // ---- fallback paths (round-6 / round-3) ----
  hipMemsetAsync(deg, 0, (size_t)NNODES*4, stream);
  k_deg<<<(NEDGES+255)/256, 256, 0, stream>>>(ei, deg);
  k_embed<<<(NNODES+31)/32, 256, 0, stream>>>(r, v, gf, embW1, embB1, embW2, embB2, h);
  for(int l = 0; l < NL; l++){
    hipMemsetAsync(agg, 0, (size_t)6400000*4, stream);
    if(big){
      k_pre<<<(NNODES+31)/32, 256, 0, stream>>>(h, msgW1 + (size_t)l*35712, P);
      k_msg2<<<NEDGES/32, 256, 0, stream>>>(ei, P, pos, v, r, dom,
          msgW1 + (size_t)l*35712, msgW2 + (size_t)l*16384,
          bb1 + l*128, msgB2 + l*128, agg);
    } else {
      k_msg_old<<<NEDGES/32, 256, 0, stream>>>(ei, h, pos, v, r, dom, gf,
          msgW1, msgB1, msgW2, msgB2, agg, l);
    }
    k_upd<<<(NNODES+31)/32, 256, 0, stream>>>(h, agg, deg, gf,
        updW1, updB1, updW2, updB2, l);
    hipMemsetAsync(sum, 0, 128*4, stream);
    hipMemsetAsync(sq,  0, 128*4, stream);
    k_stats<<<256, 256, 0, stream>>>(h, sum, sq);
    k_norm<<<25000, 256, 0, stream>>>(h, sum, sq);
  }
  hipMemsetAsync(sum, 0, 128*4, stream);
  hipMemsetAsync(sq,  0, 128*4, stream);
  k_stats<<<256, 256, 0, stream>>>(h, sum, sq);
  k_macro<<<1, 128, 0, stream>>>(sum, macW1, macB1, macW2, macB2, out);
  k_out<<<(NNODES+31)/32, 256, 0, stream>>>(h, pos, v, domn,
                                            outW1, outB1, outW2, outB2, out);
}

// Round 14
// 2450.867 us; speedup vs baseline: 1.6539x; 1.0344x over previous
//
#include <hip/hip_runtime.h>
#include <hip/hip_bf16.h>

#define NNODES 50000
#define NEDGES 300000
#define NL 6
#define AP 132   // fp32 A-tile row pitch: 128 + 4 pad

// ---------- tiny setup kernels ----------
__global__ void k_gf(const float* dom, const float* t, const float* xg,
                     const float* domn, const float* tn, float* gf){
  int i = threadIdx.x;
  if(i < 3)        gf[i]  = dom[i];
  else if(i == 3)  gf[3]  = t[0];
  else if(i < 8)   gf[i]  = xg[i-4];
  else if(i < 11)  gf[i]  = domn[i-8];
  else if(i == 11) gf[11] = tn[0];
}

__global__ void k_deg(const int* ei, float* deg){
  int e = blockIdx.x*blockDim.x + threadIdx.x;
  if(e < NEDGES) atomicAdd(&deg[ei[NEDGES + e]], 1.0f);
}

__global__ void k_histi(const int* ei, int* cnt){
  int e = blockIdx.x*blockDim.x + threadIdx.x;
  if(e < NEDGES) atomicAdd(&cnt[ei[NEDGES + e]], 1);
}

// single-block exclusive scan of cnt[NNODES] -> off[NNODES+1]
__global__ __launch_bounds__(1024) void k_scan(const int* cnt, int* off){
  __shared__ int buf[1024];
  __shared__ int carry;
  int t = threadIdx.x;
  if(t == 0) carry = 0;
  __syncthreads();
  for(int base = 0; base < NNODES; base += 1024){
    int i = base + t;
    int x = (i < NNODES) ? cnt[i] : 0;
    buf[t] = x;
    __syncthreads();
    for(int ofs = 1; ofs < 1024; ofs <<= 1){
      int y = (t >= ofs) ? buf[t-ofs] : 0;
      __syncthreads();
      buf[t] += y;
      __syncthreads();
    }
    if(i < NNODES) off[i] = carry + buf[t] - x;
    __syncthreads();
    if(t == 1023) carry += buf[1023];
    __syncthreads();
  }
  if(t == 0) off[NNODES] = carry;
}

// counting-sort scatter: edges grouped by dst
__global__ void k_scatter(const int* ei, const int* off, int* cur, int* srcP, int* dstP){
  int e = blockIdx.x*blockDim.x + threadIdx.x;
  if(e < NEDGES){
    int s = ei[e], d = ei[NEDGES + e];
    int p = atomicAdd(&cur[d], 1);
    int ix = off[d] + p;
    srcP[ix] = s; dstP[ix] = d;
  }
}

// bb1[l][c] = msgB1[l][c] + sum_j gf[j]*msgW1[l][267+j][c]
__global__ void k_gfb(const float* gf, const float* mW1, const float* mB1, float* bb1){
  int i = blockIdx.x*256 + threadIdx.x;
  if(i < 768){
    int l = i >> 7, c = i & 127;
    float s = mB1[l*128 + c];
    #pragma unroll
    for(int j=0;j<12;j++) s = fmaf(gf[j], mW1[(size_t)l*35712 + (size_t)(267+j)*128 + c], s);
    bb1[i] = s;
  }
}

// ---------- shared fp32 GEMM machinery ----------
__device__ __forceinline__ void fill_w(float* sW, const float* gW, int KC){
  for(int idx = threadIdx.x; idx < 32*32; idx += 256){
    int kk = idx >> 5, c4 = (idx & 31)*4;
    float4 w = make_float4(0.f,0.f,0.f,0.f);
    if(kk < KC) w = *(const float4*)(gW + (size_t)kk*128 + c4);
    *(float4*)(sW + kk*128 + c4) = w;
  }
}
__device__ __forceinline__ void gemm_chunk(const float* At, const float* sW,
                                           int KCp, int rg, int jc, float acc[4][4]){
  for(int kkg = 0; kkg < KCp; kkg += 4){
    float4 av[4];
    #pragma unroll
    for(int i=0;i<4;i++) av[i] = *(const float4*)(At + (rg*4+i)*AP + kkg);
    #pragma unroll
    for(int q=0;q<4;q++){
      float4 bq = *(const float4*)(sW + (kkg+q)*128 + 4*jc);
      #pragma unroll
      for(int i=0;i<4;i++){
        float aa = ((const float*)&av[i])[q];
        acc[i][0] = fmaf(aa, bq.x, acc[i][0]);
        acc[i][1] = fmaf(aa, bq.y, acc[i][1]);
        acc[i][2] = fmaf(aa, bq.z, acc[i][2]);
        acc[i][3] = fmaf(aa, bq.w, acc[i][3]);
      }
    }
  }
}
__device__ __forceinline__ void gemm_phase(const float* sA, float* sW, const float* gW,
                                           int K, int rg, int jc, float acc[4][4]){
  for(int k0 = 0; k0 < K; k0 += 32){
    int KC = (K - k0 < 32) ? (K - k0) : 32;
    __syncthreads();
    fill_w(sW, gW + (size_t)k0*128, KC);
    __syncthreads();
    gemm_chunk(sA + k0, sW, (KC+3)&~3, rg, jc, acc);
  }
}
__device__ __forceinline__ void init_bias(float acc[4][4], const float* b, int jc){
  float4 bb = *(const float4*)(b + 4*jc);
  #pragma unroll
  for(int i=0;i<4;i++){ acc[i][0]=bb.x; acc[i][1]=bb.y; acc[i][2]=bb.z; acc[i][3]=bb.w; }
}

// ---------- embedding ----------
__global__ __launch_bounds__(256) void k_embed(const float* r, const float* v, const float* gf,
    const float* W1, const float* b1, const float* W2, const float* b2, float* h){
  __shared__ __align__(16) float sA[32*AP];
  __shared__ __align__(16) float sW[32*128];
  __shared__ float sGf[12];
  int t = threadIdx.x, n0 = blockIdx.x*32;
  if(t < 12) sGf[t] = gf[t];
  __syncthreads();
  for(int idx = t; idx < 32*20; idx += 256){
    int row = idx/20, c = idx%20;
    int n = n0 + row; if(n >= NNODES) n = NNODES-1;
    float val;
    if(c == 0)      val = r[n];
    else if(c < 7)  val = v[(size_t)n*6 + (c-1)];
    else if(c < 19) val = sGf[c-7];
    else            val = 0.0f;
    sA[row*AP + c] = val;
  }
  int rg = t>>5, jc = t&31;
  float acc[4][4];
  init_bias(acc, b1, jc);
  gemm_phase(sA, sW, W1, 19, rg, jc, acc);
  __syncthreads();
  #pragma unroll
  for(int i=0;i<4;i++){
    float4 x = make_float4(fmaxf(acc[i][0],0.f), fmaxf(acc[i][1],0.f),
                           fmaxf(acc[i][2],0.f), fmaxf(acc[i][3],0.f));
    *(float4*)&sA[(rg*4+i)*AP + 4*jc] = x;
  }
  init_bias(acc, b2, jc);
  gemm_phase(sA, sW, W2, 128, rg, jc, acc);
  #pragma unroll
  for(int i=0;i<4;i++){
    int n = n0 + rg*4 + i;
    if(n < NNODES){
      float4 x = make_float4(fmaxf(acc[i][0],0.f), fmaxf(acc[i][1],0.f),
                             fmaxf(acc[i][2],0.f), fmaxf(acc[i][3],0.f));
      *(float4*)&h[(size_t)n*128 + 4*jc] = x;
    }
  }
}

// ---------- fused: [instance-norm from prev-layer stats] + P precompute ----------
__global__ __launch_bounds__(256) void k_pre2(float* h, const float* W1, float* P,
                                              const float* S, int doNorm){
  __shared__ __align__(16) float sA[32*AP];
  __shared__ __align__(16) float sW[32*128];
  __shared__ float sMu[128], sIv[128];
  int t = threadIdx.x, n0 = blockIdx.x*32;
  if(doNorm){
    if(t < 128){
      float mean = S[t] * (1.0f/NNODES);
      float var  = S[128+t] * (1.0f/NNODES) - mean*mean;
      if(var < 0.f) var = 0.f;
      sMu[t] = mean; sIv[t] = rsqrtf(var + 1e-5f);
    }
    __syncthreads();
    for(int idx = t; idx < 1024; idx += 256){
      int row = idx>>5, c4 = (idx&31)*4;
      int n = n0 + row; bool valid = (n < NNODES); if(!valid) n = NNODES-1;
      float4 x = *(const float4*)&h[(size_t)n*128 + c4];
      x.x = (x.x - sMu[c4+0])*sIv[c4+0];
      x.y = (x.y - sMu[c4+1])*sIv[c4+1];
      x.z = (x.z - sMu[c4+2])*sIv[c4+2];
      x.w = (x.w - sMu[c4+3])*sIv[c4+3];
      *(float4*)&sA[row*AP + c4] = x;
      if(valid) *(float4*)&h[(size_t)n*128 + c4] = x;  // persist normalized h
    }
  } else {
    for(int idx = t; idx < 1024; idx += 256){
      int row = idx>>5, c4 = (idx&31)*4;
      int n = n0 + row; if(n >= NNODES) n = NNODES-1;
      *(float4*)&sA[row*AP + c4] = *(const float4*)&h[(size_t)n*128 + c4];
    }
  }
  int rg = t>>5, jc = t&31;
  float acc[4][4];
  #pragma unroll
  for(int i=0;i<4;i++){ acc[i][0]=0.f; acc[i][1]=0.f; acc[i][2]=0.f; acc[i][3]=0.f; }
  gemm_phase(sA, sW, W1, 128, rg, jc, acc);               // W1a
  #pragma unroll
  for(int i=0;i<4;i++){
    int n = n0 + rg*4 + i;
    if(n < NNODES)
      *(float4*)&P[(size_t)n*256 + 4*jc] = make_float4(acc[i][0],acc[i][1],acc[i][2],acc[i][3]);
  }
  #pragma unroll
  for(int i=0;i<4;i++){ acc[i][0]=0.f; acc[i][1]=0.f; acc[i][2]=0.f; acc[i][3]=0.f; }
  gemm_phase(sA, sW, W1 + (size_t)128*128, 128, rg, jc, acc);  // W1b
  #pragma unroll
  for(int i=0;i<4;i++){
    int n = n0 + rg*4 + i;
    if(n < NNODES)
      *(float4*)&P[(size_t)n*256 + 128 + 4*jc] = make_float4(acc[i][0],acc[i][1],acc[i][2],acc[i][3]);
  }
}

// ---------- edge kernel, dst-sorted + segment-reduced scatter (round-7/9 proven) ----------
__global__ __launch_bounds__(256) void k_msg3(const int* srcP, const int* dstP, const float* P,
    const float* pos, const float* v, const float* r, const float* dom,
    const float* W1, const float* W2, const float* bb1, const float* b2, float* agg){
  __shared__ __align__(16) float sM[32*AP];
  __shared__ __align__(16) float sW[32*128];
  __shared__ float sT[32*12];
  __shared__ float sB[128];
  __shared__ int sSrc[32], sDst[32];
  int t = threadIdx.x, e0 = blockIdx.x*32;
  if(t < 32){ sSrc[t] = srcP[e0+t]; sDst[t] = dstP[e0+t]; }
  if(t >= 128) sB[t-128] = bb1[t-128];
  __syncthreads();
  for(int idx = t; idx < 352; idx += 256){
    int kk = idx>>5, c4 = (idx&31)*4;
    *(float4*)&sW[kk*128 + c4] = *(const float4*)&W1[(size_t)(256+kk)*128 + c4];
  }
  if(t < 32){
    int s = sSrc[t], d = sDst[t];
    #pragma unroll
    for(int c=0;c<3;c++){
      float dp = pos[(size_t)d*3+c] - pos[(size_t)s*3+c];
      float dm = dom[c];
      dp = dp - dm * rintf(dp/dm);
      sT[t*12 + c] = dp;
    }
    #pragma unroll
    for(int c=0;c<6;c++)
      sT[t*12 + 3 + c] = v[(size_t)d*6+c] - v[(size_t)s*6+c];
    sT[t*12 + 9]  = r[d];
    sT[t*12 + 10] = r[s];
    sT[t*12 + 11] = 0.0f;
  }
  // z1 gather via LDS staging (batched independent loads -> latency hidden)
  for(int idx = t; idx < 1024; idx += 256){
    int row = idx>>5, c4 = (idx&31)*4;
    float4 pd = *(const float4*)&P[(size_t)sDst[row]*256 + c4];
    float4 ps = *(const float4*)&P[(size_t)sSrc[row]*256 + 128 + c4];
    float4 bb = *(const float4*)&sB[c4];
    *(float4*)&sM[row*AP + c4] = make_float4(bb.x+pd.x+ps.x, bb.y+pd.y+ps.y,
                                             bb.z+pd.z+ps.z, bb.w+pd.w+ps.w);
  }
  __syncthreads();
  int rg = t>>5, jc = t&31;
  float acc[4][4];
  #pragma unroll
  for(int i=0;i<4;i++)
    #pragma unroll
    for(int c=0;c<4;c++) acc[i][c] = sM[(rg*4+i)*AP + 4*jc + c];
  for(int k=0;k<11;k++){
    float4 b = *(const float4*)&sW[k*128 + 4*jc];
    #pragma unroll
    for(int i=0;i<4;i++){
      float a = sT[(rg*4+i)*12 + k];
      acc[i][0] = fmaf(a, b.x, acc[i][0]);
      acc[i][1] = fmaf(a, b.y, acc[i][1]);
      acc[i][2] = fmaf(a, b.z, acc[i][2]);
      acc[i][3] = fmaf(a, b.w, acc[i][3]);
    }
  }
  #pragma unroll
  for(int i=0;i<4;i++){
    float4 x = make_float4(fmaxf(acc[i][0],0.f), fmaxf(acc[i][1],0.f),
                           fmaxf(acc[i][2],0.f), fmaxf(acc[i][3],0.f));
    *(float4*)&sM[(rg*4+i)*AP + 4*jc] = x;
  }
  init_bias(acc, b2, jc);
  gemm_phase(sM, sW, W2, 128, rg, jc, acc);
  __syncthreads();
  #pragma unroll
  for(int i=0;i<4;i++){
    float4 x = make_float4(fmaxf(acc[i][0],0.f), fmaxf(acc[i][1],0.f),
                           fmaxf(acc[i][2],0.f), fmaxf(acc[i][3],0.f));
    *(float4*)&sM[(rg*4+i)*AP + 4*jc] = x;
  }
  __syncthreads();
  int col = t & 127, half = t >> 7;
  int rbeg = half*16, rend = rbeg + 16;
  int cur = sDst[rbeg];
  float run = 0.f;
  for(int row = rbeg; row < rend; row++){
    run += sM[row*AP + col];
    int nxt = (row+1 < rend) ? sDst[row+1] : -1;
    if(nxt != cur){
      atomicAdd(&agg[(size_t)cur*128 + col], run);
      run = 0.f; cur = nxt;
    }
  }
}

// ---------- fused node update: h += MLP([h, agg/deg, gf]); zeros agg; stats -> S ----------
__global__ __launch_bounds__(256) void k_upd2(float* h, float* agg, const int* cnt,
    const float* gf, const float* W1, const float* b1, const float* W2, const float* b2,
    float* S){
  __shared__ __align__(16) float sA[32*AP];
  __shared__ __align__(16) float sW[32*128];
  __shared__ float pS[8*128], pQ[8*128];
  __shared__ float sGf[12], sRd[32];
  int t = threadIdx.x, n0 = blockIdx.x*32;
  if(t < 12) sGf[t] = gf[t];
  if(t < 32){
    int n = n0 + t; if(n >= NNODES) n = NNODES-1;
    sRd[t] = 1.0f / fmaxf((float)cnt[n], 1.0f);
  }
  __syncthreads();
  int rg = t>>5, jc = t&31;
  float acc[4][4];
  init_bias(acc, b1, jc);
  for(int idx = t; idx < 1024; idx += 256){
    int row = idx>>5, c4 = (idx&31)*4;
    int n = n0 + row; if(n >= NNODES) n = NNODES-1;
    *(float4*)&sA[row*AP + c4] = *(const float4*)&h[(size_t)n*128 + c4];
  }
  gemm_phase(sA, sW, W1, 128, rg, jc, acc);
  __syncthreads();
  for(int idx = t; idx < 1024; idx += 256){
    int row = idx>>5, c4 = (idx&31)*4;
    int n = n0 + row; bool valid = (n < NNODES); if(!valid) n = NNODES-1;
    float4 x = *(const float4*)&agg[(size_t)n*128 + c4];
    float rd = sRd[row];
    x.x*=rd; x.y*=rd; x.z*=rd; x.w*=rd;
    *(float4*)&sA[row*AP + c4] = x;
    if(valid) *(float4*)&agg[(size_t)n*128 + c4] = make_float4(0.f,0.f,0.f,0.f);
  }
  gemm_phase(sA, sW, W1 + (size_t)128*128, 128, rg, jc, acc);
  __syncthreads();
  if(t < 32){
    #pragma unroll
    for(int c=0;c<12;c++) sA[t*AP + c] = sGf[c];
  }
  gemm_phase(sA, sW, W1 + (size_t)256*128, 12, rg, jc, acc);
  __syncthreads();
  #pragma unroll
  for(int i=0;i<4;i++){
    float4 x = make_float4(fmaxf(acc[i][0],0.f), fmaxf(acc[i][1],0.f),
                           fmaxf(acc[i][2],0.f), fmaxf(acc[i][3],0.f));
    *(float4*)&sA[(rg*4+i)*AP + 4*jc] = x;
  }
  init_bias(acc, b2, jc);
  gemm_phase(sA, sW, W2, 128, rg, jc, acc);   // no relu
  float sc[4] = {0.f,0.f,0.f,0.f}, qc[4] = {0.f,0.f,0.f,0.f};
  #pragma unroll
  for(int i=0;i<4;i++){
    int n = n0 + rg*4 + i;
    if(n < NNODES){
      float4 x = *(const float4*)&h[(size_t)n*128 + 4*jc];
      x.x += acc[i][0]; x.y += acc[i][1]; x.z += acc[i][2]; x.w += acc[i][3];
      *(float4*)&h[(size_t)n*128 + 4*jc] = x;
      sc[0]+=x.x; sc[1]+=x.y; sc[2]+=x.z; sc[3]+=x.w;
      qc[0]+=x.x*x.x; qc[1]+=x.y*x.y; qc[2]+=x.z*x.z; qc[3]+=x.w*x.w;
    }
  }
  #pragma unroll
  for(int c=0;c<4;c++){ pS[rg*128 + 4*jc + c] = sc[c]; pQ[rg*128 + 4*jc + c] = qc[c]; }
  __syncthreads();
  if(t < 128){
    float s = 0.f, q = 0.f;
    #pragma unroll
    for(int g=0; g<8; g++){ s += pS[g*128 + t]; q += pQ[g*128 + t]; }
    atomicAdd(&S[t], s);
    atomicAdd(&S[128 + t], q);
  }
}

// ---------- fallback kernels (round-6 / round-3 tiers, verbatim) ----------
__global__ __launch_bounds__(256) void k_msg2(const int* ei, const float* P,
    const float* pos, const float* v, const float* r, const float* dom,
    const float* W1, const float* W2, const float* bb1, const float* b2, float* agg){
  __shared__ __align__(16) float sM[32*AP];
  __shared__ __align__(16) float sW[32*128];
  __shared__ float sT[32*12];
  __shared__ float sB[128];
  __shared__ int sSrc[32], sDst[32];
  int t = threadIdx.x, e0 = blockIdx.x*32;
  if(t < 32){ sSrc[t] = ei[e0+t]; sDst[t] = ei[NEDGES + e0 + t]; }
  if(t >= 128) sB[t-128] = bb1[t-128];
  __syncthreads();
  for(int idx = t; idx < 352; idx += 256){
    int kk = idx>>5, c4 = (idx&31)*4;
    *(float4*)&sW[kk*128 + c4] = *(const float4*)&W1[(size_t)(256+kk)*128 + c4];
  }
  if(t < 32){
    int s = sSrc[t], d = sDst[t];
    #pragma unroll
    for(int c=0;c<3;c++){
      float dp = pos[(size_t)d*3+c] - pos[(size_t)s*3+c];
      float dm = dom[c];
      dp = dp - dm * rintf(dp/dm);
      sT[t*12 + c] = dp;
    }
    #pragma unroll
    for(int c=0;c<6;c++)
      sT[t*12 + 3 + c] = v[(size_t)d*6+c] - v[(size_t)s*6+c];
    sT[t*12 + 9]  = r[d];
    sT[t*12 + 10] = r[s];
    sT[t*12 + 11] = 0.0f;
  }
  for(int idx = t; idx < 1024; idx += 256){
    int row = idx>>5, c4 = (idx&31)*4;
    float4 pd = *(const float4*)&P[(size_t)sDst[row]*256 + c4];
    float4 ps = *(const float4*)&P[(size_t)sSrc[row]*256 + 128 + c4];
    float4 bb = *(const float4*)&sB[c4];
    *(float4*)&sM[row*AP + c4] = make_float4(bb.x+pd.x+ps.x, bb.y+pd.y+ps.y,
                                             bb.z+pd.z+ps.z, bb.w+pd.w+ps.w);
  }
  __syncthreads();
  int rg = t>>5, jc = t&31;
  float acc[4][4];
  #pragma unroll
  for(int i=0;i<4;i++)
    #pragma unroll
    for(int c=0;c<4;c++) acc[i][c] = sM[(rg*4+i)*AP + 4*jc + c];
  for(int k=0;k<11;k++){
    float4 b = *(const float4*)&sW[k*128 + 4*jc];
    #pragma unroll
    for(int i=0;i<4;i++){
      float a = sT[(rg*4+i)*12 + k];
      acc[i][0] = fmaf(a, b.x, acc[i][0]);
      acc[i][1] = fmaf(a, b.y, acc[i][1]);
      acc[i][2] = fmaf(a, b.z, acc[i][2]);
      acc[i][3] = fmaf(a, b.w, acc[i][3]);
    }
  }
  #pragma unroll
  for(int i=0;i<4;i++){
    float4 x = make_float4(fmaxf(acc[i][0],0.f), fmaxf(acc[i][1],0.f),
                           fmaxf(acc[i][2],0.f), fmaxf(acc[i][3],0.f));
    *(float4*)&sM[(rg*4+i)*AP + 4*jc] = x;
  }
  init_bias(acc, b2, jc);
  gemm_phase(sM, sW, W2, 128, rg, jc, acc);
  #pragma unroll
  for(int i=0;i<4;i++){
    int d = sDst[rg*4+i];
    #pragma unroll
    for(int c=0;c<4;c++)
      atomicAdd(&agg[(size_t)d*128 + 4*jc + c], fmaxf(acc[i][c], 0.0f));
  }
}

__global__ __launch_bounds__(256) void k_pre(const float* h, const float* W1, float* P){
  __shared__ __align__(16) float sA[32*AP];
  __shared__ __align__(16) float sW[32*128];
  int t = threadIdx.x, n0 = blockIdx.x*32;
  for(int idx = t; idx < 1024; idx += 256){
    int row = idx>>5, c4 = (idx&31)*4;
    int n = n0 + row; if(n >= NNODES) n = NNODES-1;
    *(float4*)&sA[row*AP + c4] = *(const float4*)&h[(size_t)n*128 + c4];
  }
  int rg = t>>5, jc = t&31;
  float acc[4][4];
  #pragma unroll
  for(int i=0;i<4;i++){ acc[i][0]=0.f; acc[i][1]=0.f; acc[i][2]=0.f; acc[i][3]=0.f; }
  gemm_phase(sA, sW, W1, 128, rg, jc, acc);
  #pragma unroll
  for(int i=0;i<4;i++){
    int n = n0 + rg*4 + i;
    if(n < NNODES)
      *(float4*)&P[(size_t)n*256 + 4*jc] = make_float4(acc[i][0],acc[i][1],acc[i][2],acc[i][3]);
  }
  #pragma unroll
  for(int i=0;i<4;i++){ acc[i][0]=0.f; acc[i][1]=0.f; acc[i][2]=0.f; acc[i][3]=0.f; }
  gemm_phase(sA, sW, W1 + (size_t)128*128, 128, rg, jc, acc);
  #pragma unroll
  for(int i=0;i<4;i++){
    int n = n0 + rg*4 + i;
    if(n < NNODES)
      *(float4*)&P[(size_t)n*256 + 128 + 4*jc] = make_float4(acc[i][0],acc[i][1],acc[i][2],acc[i][3]);
  }
}

__global__ __launch_bounds__(256) void k_msg_old(const int* ei, const float* h,
    const float* pos, const float* v, const float* r, const float* dom, const float* gf,
    const float* W1, const float* b1, const float* W2, const float* b2, float* agg, int l){
  __shared__ __align__(16) float sA[32*AP];
  __shared__ __align__(16) float sW[32*128];
  __shared__ int sSrc[32], sDst[32];
  __shared__ float sGf[12];
  int t = threadIdx.x, e0 = blockIdx.x*32;
  if(t < 32){ sSrc[t] = ei[e0+t]; sDst[t] = ei[NEDGES + e0 + t]; }
  if(t >= 32 && t < 44) sGf[t-32] = gf[t-32];
  __syncthreads();
  const float* Wl1 = W1 + (size_t)l*35712;
  const float* Wl2 = W2 + (size_t)l*16384;
  const float* bl1 = b1 + l*128;
  const float* bl2 = b2 + l*128;
  int rg = t>>5, jc = t&31;
  float acc[4][4];
  init_bias(acc, bl1, jc);
  for(int idx = t; idx < 1024; idx += 256){
    int row = idx>>5, c4 = (idx&31)*4;
    *(float4*)&sA[row*AP + c4] = *(const float4*)&h[(size_t)sDst[row]*128 + c4];
  }
  gemm_phase(sA, sW, Wl1, 128, rg, jc, acc);
  __syncthreads();
  for(int idx = t; idx < 1024; idx += 256){
    int row = idx>>5, c4 = (idx&31)*4;
    *(float4*)&sA[row*AP + c4] = *(const float4*)&h[(size_t)sSrc[row]*128 + c4];
  }
  gemm_phase(sA, sW, Wl1 + (size_t)128*128, 128, rg, jc, acc);
  __syncthreads();
  if(t < 32){
    int s = sSrc[t], d = sDst[t];
    #pragma unroll
    for(int c=0;c<3;c++){
      float dp = pos[(size_t)d*3+c] - pos[(size_t)s*3+c];
      float dm = dom[c];
      dp = dp - dm * rintf(dp/dm);
      sA[t*AP + c] = dp;
    }
    #pragma unroll
    for(int c=0;c<6;c++)
      sA[t*AP + 3 + c] = v[(size_t)d*6+c] - v[(size_t)s*6+c];
    sA[t*AP + 9]  = r[d];
    sA[t*AP + 10] = r[s];
    #pragma unroll
    for(int c=0;c<12;c++) sA[t*AP + 11 + c] = sGf[c];
    sA[t*AP + 23] = 0.0f;
  }
  gemm_phase(sA, sW, Wl1 + (size_t)256*128, 23, rg, jc, acc);
  __syncthreads();
  #pragma unroll
  for(int i=0;i<4;i++){
    float4 x = make_float4(fmaxf(acc[i][0],0.f), fmaxf(acc[i][1],0.f),
                           fmaxf(acc[i][2],0.f), fmaxf(acc[i][3],0.f));
    *(float4*)&sA[(rg*4+i)*AP + 4*jc] = x;
  }
  init_bias(acc, bl2, jc);
  gemm_phase(sA, sW, Wl2, 128, rg, jc, acc);
  #pragma unroll
  for(int i=0;i<4;i++){
    int d = sDst[rg*4+i];
    #pragma unroll
    for(int c=0;c<4;c++)
      atomicAdd(&agg[(size_t)d*128 + 4*jc + c], fmaxf(acc[i][c], 0.0f));
  }
}

__global__ __launch_bounds__(256) void k_upd(float* h, const float* agg, const float* deg,
    const float* gf, const float* W1, const float* b1, const float* W2, const float* b2, int l){
  __shared__ __align__(16) float sA[32*AP];
  __shared__ __align__(16) float sW[32*128];
  __shared__ float sGf[12], sRd[32];
  int t = threadIdx.x, n0 = blockIdx.x*32;
  if(t < 12) sGf[t] = gf[t];
  if(t < 32){
    int n = n0 + t; if(n >= NNODES) n = NNODES-1;
    sRd[t] = 1.0f / fmaxf(deg[n], 1.0f);
  }
  __syncthreads();
  const float* Wl1 = W1 + (size_t)l*34304;
  const float* Wl2 = W2 + (size_t)l*16384;
  const float* bl1 = b1 + l*128;
  const float* bl2 = b2 + l*128;
  int rg = t>>5, jc = t&31;
  float acc[4][4];
  init_bias(acc, bl1, jc);
  for(int idx = t; idx < 1024; idx += 256){
    int row = idx>>5, c4 = (idx&31)*4;
    int n = n0 + row; if(n >= NNODES) n = NNODES-1;
    *(float4*)&sA[row*AP + c4] = *(const float4*)&h[(size_t)n*128 + c4];
  }
  gemm_phase(sA, sW, Wl1, 128, rg, jc, acc);
  __syncthreads();
  for(int idx = t; idx < 1024; idx += 256){
    int row = idx>>5, c4 = (idx&31)*4;
    int n = n0 + row; if(n >= NNODES) n = NNODES-1;
    float4 x = *(const float4*)&agg[(size_t)n*128 + c4];
    float rd = sRd[row];
    x.x*=rd; x.y*=rd; x.z*=rd; x.w*=rd;
    *(float4*)&sA[row*AP + c4] = x;
  }
  gemm_phase(sA, sW, Wl1 + (size_t)128*128, 128, rg, jc, acc);
  __syncthreads();
  if(t < 32){
    #pragma unroll
    for(int c=0;c<12;c++) sA[t*AP + c] = sGf[c];
  }
  gemm_phase(sA, sW, Wl1 + (size_t)256*128, 12, rg, jc, acc);
  __syncthreads();
  #pragma unroll
  for(int i=0;i<4;i++){
    float4 x = make_float4(fmaxf(acc[i][0],0.f), fmaxf(acc[i][1],0.f),
                           fmaxf(acc[i][2],0.f), fmaxf(acc[i][3],0.f));
    *(float4*)&sA[(rg*4+i)*AP + 4*jc] = x;
  }
  init_bias(acc, bl2, jc);
  gemm_phase(sA, sW, Wl2, 128, rg, jc, acc);
  #pragma unroll
  for(int i=0;i<4;i++){
    int n = n0 + rg*4 + i;
    if(n < NNODES){
      float4 x = *(const float4*)&h[(size_t)n*128 + 4*jc];
      x.x += acc[i][0]; x.y += acc[i][1]; x.z += acc[i][2]; x.w += acc[i][3];
      *(float4*)&h[(size_t)n*128 + 4*jc] = x;
    }
  }
}

// ---------- instance-norm stats / norm ----------
__global__ __launch_bounds__(256) void k_stats(const float* h, float* sum, float* sq){
  int col = threadIdx.x & 127, half = threadIdx.x >> 7;
  float s = 0.f, q = 0.f;
  for(int n = blockIdx.x*2 + half; n < NNODES; n += gridDim.x*2){
    float x = h[(size_t)n*128 + col];
    s += x; q += x*x;
  }
  __shared__ float ls[256], lq[256];
  ls[threadIdx.x] = s; lq[threadIdx.x] = q;
  __syncthreads();
  if(half == 0){
    atomicAdd(&sum[col], ls[col] + ls[128+col]);
    atomicAdd(&sq[col],  lq[col] + lq[128+col]);
  }
}

__global__ void k_norm(float* h, const float* sum, const float* sq){
  size_t i = (size_t)blockIdx.x*256 + threadIdx.x;
  if(i < (size_t)NNODES*128){
    int col = i & 127;
    float mean = sum[col] * (1.0f/NNODES);
    float var  = sq[col] * (1.0f/NNODES) - mean*mean;
    if(var < 0.f) var = 0.f;
    h[i] = (h[i] - mean) * rsqrtf(var + 1e-5f);
  }
}

// ---------- output head + epilogue ----------
__global__ __launch_bounds__(256) void k_out(const float* h, const float* pos, const float* v,
    const float* domn, const float* W1, const float* b1, const float* W2, const float* b2,
    float* out){
  __shared__ __align__(16) float sA[32*AP];
  __shared__ __align__(16) float sW[32*128];
  __shared__ float sW2[128*9], sB2[9], sDn[3];
  int t = threadIdx.x, n0 = blockIdx.x*32;
  for(int idx = t; idx < 128*9; idx += 256) sW2[idx] = W2[idx];
  if(t < 9) sB2[t] = b2[t];
  if(t >= 16 && t < 19) sDn[t-16] = domn[t-16];
  for(int idx = t; idx < 1024; idx += 256){
    int row = idx>>5, c4 = (idx&31)*4;
    int n = n0 + row; if(n >= NNODES) n = NNODES-1;
    *(float4*)&sA[row*AP + c4] = *(const float4*)&h[(size_t)n*128 + c4];
  }
  int rg = t>>5, jc = t&31;
  float acc[4][4];
  init_bias(acc, b1, jc);
  gemm_phase(sA, sW, W1, 128, rg, jc, acc);
  __syncthreads();
  #pragma unroll
  for(int i=0;i<4;i++){
    float4 x = make_float4(fmaxf(acc[i][0],0.f), fmaxf(acc[i][1],0.f),
                           fmaxf(acc[i][2],0.f), fmaxf(acc[i][3],0.f));
    *(float4*)&sA[(rg*4+i)*AP + 4*jc] = x;
  }
  __syncthreads();
  for(int idx = t; idx < 32*9; idx += 256){
    int n = idx/9, c = idx%9;
    int gn = n0 + n;
    if(gn < NNODES){
      float s = sB2[c];
      for(int k=0;k<128;k++) s = fmaf(sA[n*AP + k], sW2[k*9 + c], s);
      if(c < 3){
        float p = 0.001f*s + pos[(size_t)gn*3 + c];
        float dn = sDn[c];
        p = p - floorf(p/dn)*dn;
        out[(size_t)gn*3 + c] = p;
      } else {
        float scale = (c < 6) ? 0.001f : 0.01f;
        float p = scale*s + v[(size_t)gn*6 + (c-3)];
        out[(size_t)150000 + (size_t)gn*6 + (c-3)] = p;
      }
    }
  }
}

// ---------- macro head ----------
__global__ __launch_bounds__(128) void k_macro(const float* sum, const float* W1,
    const float* b1, const float* W2, const float* b2, float* out){
  __shared__ float hm[128], t1[128];
  int t = threadIdx.x;
  hm[t] = sum[t] * (1.0f/NNODES);
  __syncthreads();
  float s = b1[t];
  for(int k=0;k<128;k++) s = fmaf(hm[k], W1[(size_t)k*128 + t], s);
  t1[t] = fmaxf(s, 0.0f);
  __syncthreads();
  if(t < 3){
    float o = b2[t];
    for(int k=0;k<128;k++) o = fmaf(t1[k], W2[(size_t)k*3 + t], o);
    out[450000 + t] = o;
  }
}

extern "C" void kernel_launch(void* const* d_in, const int* in_sizes, int n_in,
                              void* d_out, int out_size, void* d_ws, size_t ws_size,
                              hipStream_t stream){
  const float* v    = (const float*)d_in[0];
  const float* pos  = (const float*)d_in[1];
  const float* r    = (const float*)d_in[2];
  const float* dom  = (const float*)d_in[3];
  const float* tt   = (const float*)d_in[4];
  const float* xg   = (const float*)d_in[5];
  const float* domn = (const float*)d_in[6];
  const float* tn   = (const float*)d_in[7];
  const int*   ei   = (const int*)d_in[8];
  const float* embW1=(const float*)d_in[10]; const float* embB1=(const float*)d_in[11];
  const float* embW2=(const float*)d_in[12]; const float* embB2=(const float*)d_in[13];
  const float* msgW1=(const float*)d_in[14]; const float* msgB1=(const float*)d_in[15];
  const float* msgW2=(const float*)d_in[16]; const float* msgB2=(const float*)d_in[17];
  const float* updW1=(const float*)d_in[18]; const float* updB1=(const float*)d_in[19];
  const float* updW2=(const float*)d_in[20]; const float* updB2=(const float*)d_in[21];
  const float* outW1=(const float*)d_in[22]; const float* outB1=(const float*)d_in[23];
  const float* outW2=(const float*)d_in[24]; const float* outB2=(const float*)d_in[25];
  const float* macW1=(const float*)d_in[26]; const float* macB1=(const float*)d_in[27];
  const float* macW2=(const float*)d_in[28]; const float* macB2=(const float*)d_in[29];

  float* ws = (float*)d_ws;
  const bool big    = ws_size >= (size_t)102604288;
  const bool sorted = ws_size >= (size_t)105604292;
  float* h   = ws;                       // N*128
  float* agg = ws + (size_t)6400000;     // N*128
  float* P = 0; float* deg; float* gf; float* sum; float* sq; float* bb1 = 0;
  float* Sb = 0;
  int *cnt=0, *off=0, *cur=0, *srcP=0, *dstP=0;
  if(big){
    P   = ws + (size_t)12800000;         // N*256
    deg = ws + (size_t)25600000;
    Sb  = ws + (size_t)25600000;         // fused tier reuses deg slot
    gf  = ws + (size_t)25650016;
    sum = ws + (size_t)25650048;
    sq  = ws + (size_t)25650176;
    bb1 = ws + (size_t)25650304;
    if(sorted){
      cnt  = (int*)(ws + 25651072);
      off  = (int*)(ws + 25701072);
      cur  = (int*)(ws + 25751073);
      srcP = (int*)(ws + 25801073);
      dstP = (int*)(ws + 26101073);
    }
  } else {
    deg = ws + (size_t)12800000;
    gf  = ws + (size_t)12850000;
    sum = ws + (size_t)12850016;
    sq  = ws + (size_t)12850144;
  }

  float* out = (float*)d_out;

  k_gf<<<1, 64, 0, stream>>>(dom, tt, xg, domn, tn, gf);
  if(big) k_gfb<<<3, 256, 0, stream>>>(gf, msgW1, msgB1, bb1);

  if(sorted){
    // ---- fused path (round-9 proven configuration) ----
    hipMemsetAsync(Sb, 0, 7*256*4, stream);
    hipMemsetAsync(agg, 0, (size_t)6400000*4, stream);
    hipMemsetAsync(cnt, 0, (size_t)NNODES*4, stream);
    hipMemsetAsync(cur, 0, (size_t)NNODES*4, stream);
    k_histi<<<(NEDGES+255)/256, 256, 0, stream>>>(ei, cnt);
    k_scan<<<1, 1024, 0, stream>>>(cnt, off);
    k_scatter<<<(NEDGES+255)/256, 256, 0, stream>>>(ei, off, cur, srcP, dstP);
    k_embed<<<(NNODES+31)/32, 256, 0, stream>>>(r, v, gf, embW1, embB1, embW2, embB2, h);
    for(int l = 0; l < NL; l++){
      k_pre2<<<(NNODES+31)/32, 256, 0, stream>>>(h, msgW1 + (size_t)l*35712, P,
          (l > 0) ? (Sb + (l-1)*256) : Sb, (l > 0) ? 1 : 0);
      k_msg3<<<NEDGES/32, 256, 0, stream>>>(srcP, dstP, P, pos, v, r, dom,
          msgW1 + (size_t)l*35712, msgW2 + (size_t)l*16384,
          bb1 + l*128, msgB2 + l*128, agg);
      k_upd2<<<(NNODES+31)/32, 256, 0, stream>>>(h, agg, cnt, gf,
          updW1 + (size_t)l*34304, updB1 + l*128,
          updW2 + (size_t)l*16384, updB2 + l*128, Sb + l*256);
    }
    k_norm<<<25000, 256, 0, stream>>>(h, Sb + 5*256, Sb + 5*256 + 128);
    k_stats<<<256, 256, 0, stream>>>(h, Sb + 6*256, Sb + 6*256 + 128);
    k_macro<<<1, 128, 0, stream>>>(Sb + 6*256, macW1, macB1, macW2, macB2, out);
    k_out<<<(NNODES+31)/32, 256, 0, stream>>>(h, pos, v, domn,
                                              outW1, outB1, outW2, outB2, out);
    return;
  }

  // ---- fallback paths (round-6 / round-3) ----
  hipMemsetAsync(deg, 0, (size_t)NNODES*4, stream);
  k_deg<<<(NEDGES+255)/256, 256, 0, stream>>>(ei, deg);
  k_embed<<<(NNODES+31)/32, 256, 0, stream>>>(r, v, gf, embW1, embB1, embW2, embB2, h);
  for(int l = 0; l < NL; l++){
    hipMemsetAsync(agg, 0, (size_t)6400000*4, stream);
    if(big){
      k_pre<<<(NNODES+31)/32, 256, 0, stream>>>(h, msgW1 + (size_t)l*35712, P);
      k_msg2<<<NEDGES/32, 256, 0, stream>>>(ei, P, pos, v, r, dom,
          msgW1 + (size_t)l*35712, msgW2 + (size_t)l*16384,
          bb1 + l*128, msgB2 + l*128, agg);
    } else {
      k_msg_old<<<NEDGES/32, 256, 0, stream>>>(ei, h, pos, v, r, dom, gf,
          msgW1, msgB1, msgW2, msgB2, agg, l);
    }
    k_upd<<<(NNODES+31)/32, 256, 0, stream>>>(h, agg, deg, gf,
        updW1, updB1, updW2, updB2, l);
    hipMemsetAsync(sum, 0, 128*4, stream);
    hipMemsetAsync(sq,  0, 128*4, stream);
    k_stats<<<256, 256, 0, stream>>>(h, sum, sq);
    k_norm<<<25000, 256, 0, stream>>>(h, sum, sq);
  }
  hipMemsetAsync(sum, 0, 128*4, stream);
  hipMemsetAsync(sq,  0, 128*4, stream);
  k_stats<<<256, 256, 0, stream>>>(h, sum, sq);
  k_macro<<<1, 128, 0, stream>>>(sum, macW1, macB1, macW2, macB2, out);
  k_out<<<(NNODES+31)/32, 256, 0, stream>>>(h, pos, v, domn,
                                            outW1, outB1, outW2, outB2, out);
}